// Round 1
// baseline (1117.904 us; speedup 1.0000x reference)
//
#include <hip/hip_runtime.h>
#include <hip/hip_bf16.h>

#define NN   16384
#define EE   65536
#define GG   64
#define INF  63
#define HID  2048
#define MID  1024
#define NCLS 18
#define EPS  1e-5f
#define SLOPE 0.01f
#define MR   (NN / 128)   // 128 block-rows for layer-1 BN partials

typedef unsigned short ushort;
typedef unsigned int uint;

using bf16x8 = __attribute__((ext_vector_type(8))) __bf16;
using f32x4  = __attribute__((ext_vector_type(4))) float;

__device__ __forceinline__ ushort f2us(float x) {
    __hip_bfloat16 b = __float2bfloat16(x);
    return __builtin_bit_cast(ushort, b);
}
__device__ __forceinline__ float us2f(ushort u) {
    return __bfloat162float(__builtin_bit_cast(__hip_bfloat16, u));
}

// async global->LDS, 16B per lane; LDS base wave-uniform, HW adds lane*16
__device__ __forceinline__ void gll16(const ushort* g, ushort* l) {
    __builtin_amdgcn_global_load_lds(
        (const __attribute__((address_space(1))) uint*)g,
        (__attribute__((address_space(3))) uint*)l, 16, 0, 0);
}

// ---------------- utility ----------------

__global__ void k_zero_i(int* __restrict__ p, int n) {
    int i = blockIdx.x * blockDim.x + threadIdx.x;
    if (i < n) p[i] = 0;
}

// ---------------- CSR build (by dst) ----------------

__global__ void k_count(const int* __restrict__ dst, int* __restrict__ cnt) {
    int e = blockIdx.x * blockDim.x + threadIdx.x;
    if (e < EE) atomicAdd(&cnt[dst[e]], 1);
}

__global__ void k_scan(const int* __restrict__ cnt, int* __restrict__ off,
                       float* __restrict__ deg) {
    __shared__ int sh[1024];
    int t = threadIdx.x;
    int base = t * 16;
    int loc[16];
    int s = 0;
#pragma unroll
    for (int i = 0; i < 16; ++i) {
        int c = cnt[base + i];
        loc[i] = s;
        s += c;
        deg[base + i] = (float)c;
    }
    sh[t] = s;
    __syncthreads();
    for (int d = 1; d < 1024; d <<= 1) {
        int v = (t >= d) ? sh[t - d] : 0;
        __syncthreads();
        sh[t] += v;
        __syncthreads();
    }
    int excl = sh[t] - s;
#pragma unroll
    for (int i = 0; i < 16; ++i) off[base + i] = excl + loc[i];
    if (t == 1023) off[NN] = sh[1023];
}

__global__ void k_fill(const int* __restrict__ src, const int* __restrict__ dst,
                       const int* __restrict__ off, int* __restrict__ cur,
                       int* __restrict__ csr_src) {
    int e = blockIdx.x * blockDim.x + threadIdx.x;
    if (e < EE) {
        int d = dst[e];
        int p = atomicAdd(&cur[d], 1);
        csr_src[off[d] + p] = src[e];
    }
}

// ---------------- layer-1 prep (into concat [NN,128]) ----------------

__global__ void k_h2bf_c(const float* __restrict__ h, ushort* __restrict__ Xc) {
    int i = blockIdx.x * 256 + threadIdx.x;  // over NN*64
    int r = i >> 6, c = i & 63;
    Xc[(size_t)r * 128 + c] = (c < INF) ? f2us(h[(size_t)r * INF + c]) : (ushort)0;
}

__global__ void k_agg_small_c(const float* __restrict__ X, ushort* __restrict__ Xc,
                              const int* __restrict__ off, const int* __restrict__ csr_src,
                              const float* __restrict__ deg) {
    int v = blockIdx.x;
    int f = threadIdx.x;  // 64
    float acc = 0.f;
    if (f < INF) {
        int s = off[v], e = off[v + 1];
        for (int i = s; i < e; ++i) acc += X[(size_t)csr_src[i] * INF + f];
        acc /= fmaxf(deg[v], 1.f);
    }
    Xc[(size_t)v * 128 + 64 + f] = f2us(acc);
}

// ---------------- fused BN-apply + aggregation ----------------

__global__ void k_aggbn(const ushort* __restrict__ Ybf,
                        const float* __restrict__ sc8, const float* __restrict__ sh8,
                        ushort* __restrict__ X, ushort* __restrict__ AggX,
                        const int* __restrict__ off, const int* __restrict__ csr_src,
                        const float* __restrict__ deg) {
    int v = blockIdx.x;
    int t = threadIdx.x;
    int c = t * 8;
    float sc[8], sh[8];
    *(float4*)&sc[0] = *(const float4*)&sc8[c];
    *(float4*)&sc[4] = *(const float4*)&sc8[c + 4];
    *(float4*)&sh[0] = *(const float4*)&sh8[c];
    *(float4*)&sh[4] = *(const float4*)&sh8[c + 4];

    // own row
    {
        uint4 u = ((const uint4*)(Ybf + (size_t)v * HID))[t];
        uint wds[4] = {u.x, u.y, u.z, u.w};
        uint o[4];
#pragma unroll
        for (int j = 0; j < 4; ++j) {
            float a = sc[2 * j] * us2f((ushort)(wds[j] & 0xffffu)) + sh[2 * j];
            float b = sc[2 * j + 1] * us2f((ushort)(wds[j] >> 16)) + sh[2 * j + 1];
            a = a > 0.f ? a : SLOPE * a;
            b = b > 0.f ? b : SLOPE * b;
            o[j] = (uint)f2us(a) | ((uint)f2us(b) << 16);
        }
        ((uint4*)(X + (size_t)v * HID))[t] = make_uint4(o[0], o[1], o[2], o[3]);
    }

    // neighbor mean
    int s = off[v], e = off[v + 1];
    float acc[8];
#pragma unroll
    for (int j = 0; j < 8; ++j) acc[j] = 0.f;
    for (int i = s; i < e; ++i) {
        uint4 u = ((const uint4*)(Ybf + (size_t)csr_src[i] * HID))[t];
        uint wds[4] = {u.x, u.y, u.z, u.w};
#pragma unroll
        for (int j = 0; j < 4; ++j) {
            float a = sc[2 * j] * us2f((ushort)(wds[j] & 0xffffu)) + sh[2 * j];
            float b = sc[2 * j + 1] * us2f((ushort)(wds[j] >> 16)) + sh[2 * j + 1];
            acc[2 * j]     += a > 0.f ? a : SLOPE * a;
            acc[2 * j + 1] += b > 0.f ? b : SLOPE * b;
        }
    }
    float inv = 1.f / fmaxf(deg[v], 1.f);
    uint o[4];
#pragma unroll
    for (int j = 0; j < 4; ++j)
        o[j] = (uint)f2us(acc[2 * j] * inv) | ((uint)f2us(acc[2 * j + 1] * inv) << 16);
    ((uint4*)(AggX + (size_t)v * HID))[t] = make_uint4(o[0], o[1], o[2], o[3]);
}

// ---------------- weight transposes ----------------

__global__ void k_wt2(const float* __restrict__ W0, const float* __restrict__ W1,
                      int K, int N, ushort* __restrict__ Wt0, ushort* __restrict__ Wt1,
                      int Kp) {
    const float* W = blockIdx.z ? W1 : W0;
    ushort* Wt = blockIdx.z ? Wt1 : Wt0;
    __shared__ float t[32][33];
    int kb = blockIdx.y * 32, nb = blockIdx.x * 32;
    int tx = threadIdx.x & 31, ty = threadIdx.x >> 5;
#pragma unroll
    for (int i = 0; i < 32; i += 8) {
        int k = kb + ty + i;
        t[ty + i][tx] = (k < K) ? W[(size_t)k * N + nb + tx] : 0.f;
    }
    __syncthreads();
#pragma unroll
    for (int i = 0; i < 32; i += 8)
        Wt[(size_t)(nb + ty + i) * Kp + kb + tx] = f2us(t[tx][ty + i]);
}

__global__ void k_wt2c(const float* __restrict__ W0, const float* __restrict__ W1,
                       int Kw, int N, ushort* __restrict__ Wtc, int KP) {
    const float* W = blockIdx.z ? W1 : W0;
    const int kOff = blockIdx.z ? (KP / 2) : 0;
    __shared__ float t[32][33];
    int kb = blockIdx.y * 32, nb = blockIdx.x * 32;
    int tx = threadIdx.x & 31, ty = threadIdx.x >> 5;
#pragma unroll
    for (int i = 0; i < 32; i += 8) {
        int k = kb + ty + i;
        t[ty + i][tx] = (k < Kw) ? W[(size_t)k * N + nb + tx] : 0.f;
    }
    __syncthreads();
#pragma unroll
    for (int i = 0; i < 32; i += 8)
        Wtc[(size_t)(nb + ty + i) * KP + kOff + kb + tx] = f2us(t[tx][ty + i]);
}

__global__ void k_wt(const float* __restrict__ W, int K, int N,
                     ushort* __restrict__ Wt, int Kp) {
    __shared__ float t[32][33];
    int kb = blockIdx.y * 32, nb = blockIdx.x * 32;
    int tx = threadIdx.x & 31, ty = threadIdx.x >> 5;
#pragma unroll
    for (int i = 0; i < 32; i += 8) {
        int k = kb + ty + i;
        t[ty + i][tx] = (k < K) ? W[(size_t)k * N + nb + tx] : 0.f;
    }
    __syncthreads();
#pragma unroll
    for (int i = 0; i < 32; i += 8)
        Wt[(size_t)(nb + ty + i) * Kp + kb + tx] = f2us(t[tx][ty + i]);
}

// ---------------- MFMA GEMM, 128x128 two-pass (layer-1 + head) ------------

#define BK 64

__global__ __launch_bounds__(256)
void k_mgemm(const ushort* __restrict__ A1, int lda1, const ushort* __restrict__ B1t, int ldb1, int K1,
             const ushort* __restrict__ A2, int lda2, const ushort* __restrict__ B2t, int ldb2, int K2,
             const float* __restrict__ bias, float* __restrict__ Cf, ushort* __restrict__ Cbf,
             int ldc, int fuse_lrelu, float* __restrict__ s1p, float* __restrict__ s2p,
             size_t cStrideZ) {
    __shared__ __align__(16) ushort As[128 * BK];
    __shared__ __align__(16) ushort Bs[128 * BK];
    __shared__ float sb1[4][64];
    __shared__ float sb2[4][64];
    const int tid = threadIdx.x;
    const int lane = tid & 63;
    const int w = tid >> 6;
    const int rowBase = blockIdx.y * 128;
    const int colBase = blockIdx.x * 128;
    const int m0 = (w & 1) * 64;
    const int n0 = (w >> 1) * 64;
    const int z = blockIdx.z;
    A1 += (size_t)z * K1;
    B1t += (size_t)z * K1;
    if (Cf) Cf += (size_t)z * cStrideZ;

    f32x4 acc[4][4];
#pragma unroll
    for (int mi = 0; mi < 4; ++mi)
#pragma unroll
        for (int ni = 0; ni < 4; ++ni) acc[mi][ni] = (f32x4){0.f, 0.f, 0.f, 0.f};

    const int lrow = w * 8 + (lane >> 3);
    const int gc8 = ((lane & 7) ^ (lane >> 3)) * 8;
    const int la = lane & 15, q = lane >> 4;
    const int la7 = lane & 7;

    for (int pass = 0; pass < 2; ++pass) {
        const ushort* A  = pass ? A2 : A1;
        const ushort* Bt = pass ? B2t : B1t;
        const int K   = pass ? K2 : K1;
        const int lda = pass ? lda2 : lda1;
        const int ldb = pass ? ldb2 : ldb1;
        if (A == nullptr) continue;
        const ushort* gA = A + (size_t)(rowBase + lrow) * lda + gc8;
        const ushort* gB = Bt + (size_t)(colBase + lrow) * ldb + gc8;
        for (int kt = 0; kt < K; kt += BK) {
#pragma unroll
            for (int j = 0; j < 4; ++j) {
                gll16(gA + (size_t)(j * 32) * lda + kt, As + j * 2048 + w * 512);
                gll16(gB + (size_t)(j * 32) * ldb + kt, Bs + j * 2048 + w * 512);
            }
            __syncthreads();
#pragma unroll
            for (int kk = 0; kk < 2; ++kk) {
                const int lc8 = ((kk * 4 + q) ^ la7) * 8;
                bf16x8 av[4], bv[4];
#pragma unroll
                for (int mi = 0; mi < 4; ++mi)
                    av[mi] = *(const bf16x8*)&As[(m0 + mi * 16 + la) * BK + lc8];
#pragma unroll
                for (int ni = 0; ni < 4; ++ni)
                    bv[ni] = *(const bf16x8*)&Bs[(n0 + ni * 16 + la) * BK + lc8];
#pragma unroll
                for (int mi = 0; mi < 4; ++mi)
#pragma unroll
                    for (int ni = 0; ni < 4; ++ni)
                        acc[mi][ni] = __builtin_amdgcn_mfma_f32_16x16x32_bf16(
                            av[mi], bv[ni], acc[mi][ni], 0, 0, 0);
            }
            __syncthreads();
        }
    }

#pragma unroll
    for (int mi = 0; mi < 4; ++mi) {
#pragma unroll
        for (int ni = 0; ni < 4; ++ni) {
            const int lc = colBase + n0 + ni * 16 + la;
            const float bv = bias ? bias[lc] : 0.f;
#pragma unroll
            for (int r = 0; r < 4; ++r) {
                const int row = rowBase + m0 + mi * 16 + q * 4 + r;
                float v = acc[mi][ni][r] + bv;
                if (fuse_lrelu) v = v > 0.f ? v : SLOPE * v;
                if (Cbf) Cbf[(size_t)row * ldc + lc] = f2us(v);
                else     Cf[(size_t)row * ldc + lc] = v;
            }
        }
    }

    if (s1p) {
#pragma unroll
        for (int ni = 0; ni < 4; ++ni) {
            const int lc = colBase + n0 + ni * 16 + la;
            const float bv = bias ? bias[lc] : 0.f;
            float t1 = 0.f, t2 = 0.f;
#pragma unroll
            for (int mi = 0; mi < 4; ++mi)
#pragma unroll
                for (int r = 0; r < 4; ++r) {
                    float v = acc[mi][ni][r] + bv;
                    t1 += v;
                    t2 += v * v;
                }
            t1 += __shfl_xor(t1, 16);
            t1 += __shfl_xor(t1, 32);
            t2 += __shfl_xor(t2, 16);
            t2 += __shfl_xor(t2, 32);
            if (q == 0) {
                sb1[w][ni * 16 + la] = t1;
                sb2[w][ni * 16 + la] = t2;
            }
        }
        __syncthreads();
        if (tid < 128) {
            int half = tid >> 6, j = tid & 63;
            float v1 = sb1[2 * half][j] + sb1[2 * half + 1][j];
            float v2 = sb2[2 * half][j] + sb2[2 * half + 1][j];
            size_t o = (size_t)blockIdx.y * ldc + colBase + half * 64 + j;
            s1p[o] = v1;
            s2p[o] = v2;
        }
    }
}

// ---------------- MFMA GEMM, 256x256 8-phase pipelined (layers 2/3) --------
// C = A1@B1t^T + A2@B2t^T + bias, all ld = HID, K1=K2 multiples of 64.
// 512 thr = 8 waves (2 wm x 4 wn); per-wave 128x64 out; BK=64.
// LDS: 2 dbuf x {A0,A1,B0,B1} halves of [128][64], 16B-chunk XOR swizzle
// (chunk c of row r holds global chunk c^(r&7); reader XORs back -> 0-conf).
// Schedule: 4 phases/K-tile, quadrants (m-half x n-half). Phase p stages one
// half of a FUTURE tile 5 phases ahead of its first ds_read; counted
// s_waitcnt vmcnt(6) at ends of phases 0,1,3 (never 0 in the loop); raw
// s_barrier x2 per phase; setprio(1) around the 16-MFMA cluster.
// Issue/use/overwrite schedule (tile t, buf=t&1):
//   stage: p0->B0(t+1), p1->A1(t+1), p2->B1(t+1), p3->A0(t+2)
//   reads: p0:{A0,B0} p1:{A1,B0} p2:{A0,B1} p3:{A1,B1}
//   every staged half is vmcnt(6)-guaranteed before first read; every region's
//   overwrite issue is >=1 barrier after its last read. Tail stages clamp to
//   kti=KT-1 (dummy into dead regions) to keep vmcnt counts uniform.

#define STAGEH(kti_, wh_) do {                                                 \
    int _kt = (kti_);                                                          \
    int _ktc = _kt < KT ? _kt : KT - 1;                                        \
    int _pass = (_ktc >= kt1);                                                 \
    int _k0 = (_ktc - (_pass ? kt1 : 0)) << 6;                                 \
    const ushort* _M;                                                          \
    int _h, _slot;                                                             \
    if ((wh_) == 0)      { _M = (_pass ? A2 : A1) + (size_t)rowBase * HID; _h = 0; _slot = 0; } \
    else if ((wh_) == 2) { _M = (_pass ? A2 : A1) + (size_t)rowBase * HID; _h = 1; _slot = 1; } \
    else if ((wh_) == 1) { _M = (_pass ? B2t : B1t) + (size_t)colBase * HID; _h = 0; _slot = 2; } \
    else                 { _M = (_pass ? B2t : B1t) + (size_t)colBase * HID; _h = 1; _slot = 3; } \
    const ushort* _g = _M + (size_t)(_h * 128 + srow) * HID + (size_t)(_k0 + sch); \
    ushort* _l = &lds[_kt & 1][_slot][0] + ldsl;                               \
    gll16(_g, _l);                                                             \
    gll16(_g + (size_t)64 * HID, _l + 4096);                                   \
} while (0)

#define PHASE(buf_, hm_, hn_, loadB_, skti_, swh_, wait_) do {                 \
    const ushort* _Ah = &lds[(buf_)][(hm_)][0];                                \
    if (loadB_) {                                                              \
        const ushort* _Bh = &lds[(buf_)][2 + (hn_)][0];                        \
        _Pragma("unroll")                                                      \
        for (int g_ = 0; g_ < 2; ++g_) {                                       \
            b[g_][0] = *(const bf16x8*)&_Bh[brb + g_ * 4096 + c0];             \
            b[g_][1] = *(const bf16x8*)&_Bh[brb + g_ * 4096 + c1];             \
        }                                                                      \
    }                                                                          \
    _Pragma("unroll")                                                          \
    for (int f_ = 0; f_ < 4; ++f_) {                                           \
        a[f_][0] = *(const bf16x8*)&_Ah[arb + f_ * 2048 + c0];                 \
        a[f_][1] = *(const bf16x8*)&_Ah[arb + f_ * 2048 + c1];                 \
    }                                                                          \
    STAGEH((skti_), (swh_));                                                   \
    __builtin_amdgcn_s_barrier();                                              \
    __builtin_amdgcn_s_setprio(1);                                             \
    _Pragma("unroll")                                                          \
    for (int kk_ = 0; kk_ < 2; ++kk_)                                          \
        _Pragma("unroll")                                                      \
        for (int f_ = 0; f_ < 4; ++f_)                                         \
            _Pragma("unroll")                                                  \
            for (int g_ = 0; g_ < 2; ++g_)                                     \
                acc[(hm_) * 4 + f_][(hn_) * 2 + g_] =                          \
                    __builtin_amdgcn_mfma_f32_16x16x32_bf16(                   \
                        a[f_][kk_], b[g_][kk_],                                \
                        acc[(hm_) * 4 + f_][(hn_) * 2 + g_], 0, 0, 0);         \
    __builtin_amdgcn_s_setprio(0);                                             \
    if (wait_) asm volatile("s_waitcnt vmcnt(6)" ::: "memory");                \
    __builtin_amdgcn_s_barrier();                                              \
} while (0)

__global__ __launch_bounds__(512, 2)
void k_mgemm256(const ushort* __restrict__ A1, const ushort* __restrict__ B1t,
                const ushort* __restrict__ A2, const ushort* __restrict__ B2t,
                int K1, int K2,
                const float* __restrict__ bias, ushort* __restrict__ Cbf,
                float* __restrict__ s1p, float* __restrict__ s2p) {
    __shared__ __align__(16) ushort lds[2][4][128 * 64];   // 128 KiB
    __shared__ float sb1[2][256];
    __shared__ float sb2[2][256];

    const int tid  = threadIdx.x;
    const int w    = tid >> 6, lane = tid & 63;
    const int la   = lane & 15, q = lane >> 4, la7 = lane & 7;
    const int wm   = w >> 2, wn = w & 3;

    // XCD-aware bijective chunk swizzle (nwg = 8*64 = 512, 512%8==0)
    const int nx  = gridDim.x;                       // 8
    const int lin = blockIdx.y * nx + blockIdx.x;
    const int cpx = (nx * gridDim.y) >> 3;           // 64
    const int swz = (lin & 7) * cpx + (lin >> 3);
    const int bx  = swz & (nx - 1), by = swz / nx;
    const int rowBase = by * 256, colBase = bx * 256;

    const int kt1 = K1 >> 6;
    const int KT  = kt1 + (K2 >> 6);

    // staging lane mapping: row = srow(+64), chunk = tid&7, global chunk XOR'd
    const int srow = tid >> 3;                        // 0..63
    const int sch  = ((tid & 7) ^ (srow & 7)) << 3;   // element offset in k
    const int ldsl = w << 9;                          // wave-uniform (1KiB/wave)

    // reader offsets (elements)
    const int arb = (wm * 16 + la) * 64;
    const int brb = (wn * 16 + la) * 64;
    const int c0  = ((0 + q) ^ la7) << 3;             // kk=0 chunk
    const int c1  = ((4 + q) ^ la7) << 3;             // kk=1 chunk

    f32x4 acc[8][4];
#pragma unroll
    for (int mi = 0; mi < 8; ++mi)
#pragma unroll
        for (int ni = 0; ni < 4; ++ni) acc[mi][ni] = (f32x4){0.f, 0.f, 0.f, 0.f};
    bf16x8 a[4][2], b[2][2];

    // prologue: tile0 {A0,B0,A1,B1} + tile1 A0 ; A0(0),B0(0) guaranteed
    STAGEH(0, 0); STAGEH(0, 1); STAGEH(0, 2); STAGEH(0, 3);
    STAGEH(1, 0);
    asm volatile("s_waitcnt vmcnt(6)" ::: "memory");
    __builtin_amdgcn_s_barrier();

    for (int t = 0; t < KT; ++t) {
        const int bf_ = t & 1;
        PHASE(bf_, 0, 0, 1, t + 1, 1, 1);   // reads A0,B0 ; stage B0(t+1)
        PHASE(bf_, 1, 0, 0, t + 1, 2, 1);   // reads A1    ; stage A1(t+1)
        PHASE(bf_, 0, 1, 1, t + 1, 3, 0);   // reads B1    ; stage B1(t+1)
        PHASE(bf_, 1, 1, 0, t + 2, 0, 1);   //             ; stage A0(t+2)
    }

    __syncthreads();   // drain everything before epilogue

    // C store (per MFMA: M-row = q*4+r, N-col = la)
#pragma unroll
    for (int mi = 0; mi < 8; ++mi) {
        const int row = rowBase + (mi >> 2) * 128 + wm * 16 + (mi & 3) * 32 + q * 4;
#pragma unroll
        for (int ni = 0; ni < 4; ++ni) {
            const int col = colBase + (ni >> 1) * 128 + wn * 16 + (ni & 1) * 64 + la;
            const float bv = bias[col];
#pragma unroll
            for (int r = 0; r < 4; ++r) {
                float v = acc[mi][ni][r] + bv;
                Cbf[(size_t)(row + r) * HID + col] = f2us(v);
            }
        }
    }

    // fused BN partial stats (pre-activation, fp32 exact)
#pragma unroll
    for (int ni = 0; ni < 4; ++ni) {
        const int cib = (ni >> 1) * 128 + wn * 16 + (ni & 1) * 64 + la;
        const float bv = bias[colBase + cib];
        float t1 = 0.f, t2 = 0.f;
#pragma unroll
        for (int mi = 0; mi < 8; ++mi)
#pragma unroll
            for (int r = 0; r < 4; ++r) {
                float v = acc[mi][ni][r] + bv;
                t1 += v;
                t2 += v * v;
            }
        t1 += __shfl_xor(t1, 16);
        t1 += __shfl_xor(t1, 32);
        t2 += __shfl_xor(t2, 16);
        t2 += __shfl_xor(t2, 32);
        if (q == 0) { sb1[wm][cib] = t1; sb2[wm][cib] = t2; }
    }
    __syncthreads();
    if (tid < 256) {
        size_t o = (size_t)by * HID + colBase + tid;
        s1p[o] = sb1[0][tid] + sb1[1][tid];
        s2p[o] = sb2[0][tid] + sb2[1][tid];
    }
}

// ---------------- BatchNorm finalize ----------------

__global__ void k_bn_finalize(const float* __restrict__ p1, const float* __restrict__ p2,
                              const float* __restrict__ gamma, const float* __restrict__ beta,
                              float* __restrict__ scale, float* __restrict__ shift, int nrb) {
    int c = blockIdx.x * 256 + threadIdx.x;
    if (c >= HID) return;
    float s1 = 0.f, s2 = 0.f;
    for (int rb = 0; rb < nrb; ++rb) {
        s1 += p1[(size_t)rb * HID + c];
        s2 += p2[(size_t)rb * HID + c];
    }
    float mean = s1 * (1.f / (float)NN);
    float var = s2 * (1.f / (float)NN) - mean * mean;
    var = fmaxf(var, 0.f);
    float sc = gamma[c] * rsqrtf(var + EPS);
    scale[c] = sc;
    shift[c] = beta[c] - mean * sc;
}

// ---------------- fused BN + pooling ----------------

__global__ void k_poolbn(const ushort* __restrict__ Ybf,
                         const float* __restrict__ scale, const float* __restrict__ shift,
                         const int* __restrict__ gstart, ushort* __restrict__ hgbf) {
    int g = blockIdx.y;
    int col = blockIdx.x * 256 + threadIdx.x;
    if (g >= GG) {
        hgbf[(size_t)g * HID + col] = 0;
        return;
    }
    int s = gstart[g], e = gstart[g + 1];
    float sc = scale[col], sh = shift[col];
    float acc = 0.f;
    for (int n = s; n < e; ++n) {
        float v = sc * us2f(Ybf[(size_t)n * HID + col]) + sh;
        acc += v > 0.f ? v : SLOPE * v;
    }
    hgbf[(size_t)g * HID + col] = f2us(acc / fmaxf((float)(e - s), 1.f));
}

__global__ void k_gstart(const int* __restrict__ gid, int* __restrict__ gstart) {
    int g = threadIdx.x;
    if (g > GG) return;
    int lo = 0, hi = NN;
    while (lo < hi) {
        int mid = (lo + hi) >> 1;
        if (gid[mid] < g) lo = mid + 1; else hi = mid;
    }
    gstart[g] = lo;
}

// ---------------- split-K reduce for head GEMMs ----------------

__global__ void k_redhead(const float* __restrict__ part, int P, size_t strideZ,
                          const float* __restrict__ bias, int ldc,
                          ushort* __restrict__ obf, float* __restrict__ of, int n) {
    int i = blockIdx.x * 256 + threadIdx.x;
    if (i >= n) return;
    float s = 0.f;
    for (int p = 0; p < P; ++p) s += part[(size_t)p * strideZ + i];
    s += bias[i % ldc];
    s = s > 0.f ? s : SLOPE * s;
    if (obf) obf[i] = f2us(s);
    else     of[i] = s;
}

__global__ void k_fc3(const float* __restrict__ x2, const float* __restrict__ W,
                      const float* __restrict__ b, float* __restrict__ out) {
    int g = blockIdx.x;
    int tid = threadIdx.x;
    float part[NCLS];
#pragma unroll
    for (int c = 0; c < NCLS; ++c) part[c] = 0.f;
    for (int k = tid; k < MID; k += 256) {
        float x = x2[(size_t)g * MID + k];
        const float* wr = W + (size_t)k * NCLS;
#pragma unroll
        for (int c = 0; c < NCLS; ++c) part[c] += x * wr[c];
    }
    __shared__ float red[4][NCLS];
    int lane = tid & 63, w = tid >> 6;
#pragma unroll
    for (int c = 0; c < NCLS; ++c) {
        float v = part[c];
        for (int o = 32; o > 0; o >>= 1) v += __shfl_down(v, o, 64);
        if (lane == 0) red[w][c] = v;
    }
    __syncthreads();
    if (tid < NCLS)
        out[(size_t)g * NCLS + tid] = red[0][tid] + red[1][tid] + red[2][tid] + red[3][tid] + b[tid];
}

// ---------------- launcher ----------------

extern "C" void kernel_launch(void* const* d_in, const int* in_sizes, int n_in,
                              void* d_out, int out_size, void* d_ws, size_t ws_size,
                              hipStream_t stream) {
    const float* h        = (const float*)d_in[0];
    const int*   src      = (const int*)d_in[1];
    const int*   dst      = (const int*)d_in[2];
    const int*   graph_id = (const int*)d_in[3];
    const float* Ws1 = (const float*)d_in[4];
    const float* Wn1 = (const float*)d_in[5];
    const float* b1  = (const float*)d_in[6];
    const float* Ws2 = (const float*)d_in[7];
    const float* Wn2 = (const float*)d_in[8];
    const float* b2  = (const float*)d_in[9];
    const float* Ws3 = (const float*)d_in[10];
    const float* Wn3 = (const float*)d_in[11];
    const float* b3  = (const float*)d_in[12];
    const float* g1  = (const float*)d_in[13];
    const float* be1 = (const float*)d_in[14];
    const float* g2  = (const float*)d_in[15];
    const float* be2 = (const float*)d_in[16];
    const float* g3  = (const float*)d_in[17];
    const float* be3 = (const float*)d_in[18];
    const float* fc1_w = (const float*)d_in[19];
    const float* fc1_b = (const float*)d_in[20];
    const float* fc2_w = (const float*)d_in[21];
    const float* fc2_b = (const float*)d_in[22];
    const float* fc3_w = (const float*)d_in[23];
    const float* fc3_b = (const float*)d_in[24];
    float* out = (float*)d_out;

    size_t off_b = 0;
    auto alloc = [&](size_t bytes) -> void* {
        void* p = (char*)d_ws + off_b;
        off_b += (bytes + 255) & ~(size_t)255;
        return p;
    };
    ushort* Wt0    = (ushort*)alloc((size_t)2 * HID * HID * 2);  // 16 MiB (2 slots)
    ushort* Wt1    = Wt0 + (size_t)HID * HID;
    ushort* X      = (ushort*)alloc((size_t)NN * HID * 2);       // 64 MiB
    ushort* AggX   = (ushort*)alloc((size_t)NN * HID * 2);       // 64 MiB
    ushort* Ybf    = (ushort*)alloc((size_t)NN * HID * 2);       // 64 MiB
    float*  deg    = (float*)alloc((size_t)NN * 4);
    int*    csroff = (int*)alloc((size_t)(NN + 1) * 4);
    int*    cursor = (int*)alloc((size_t)NN * 4);
    int*    csrsrc = (int*)alloc((size_t)EE * 4);
    float*  p1     = (float*)alloc((size_t)MR * HID * 4);        // 1 MiB
    float*  p2     = (float*)alloc((size_t)MR * HID * 4);        // 1 MiB
    float*  bnsc   = (float*)alloc((size_t)HID * 4);
    float*  bnsh   = (float*)alloc((size_t)HID * 4);
    int*    gstart = (int*)alloc((size_t)(GG + 1) * 4);

    ushort* Xc128 = X;
    ushort* hgbf  = AggX;
    ushort* x1bf  = AggX + (size_t)128 * HID;
    float*  x2f   = (float*)(AggX + (size_t)2 * 128 * HID);
    float*  partF = (float*)(AggX + (size_t)3 * 128 * HID);

    // ---- CSR build ----
    k_zero_i<<<dim3(NN / 256), dim3(256), 0, stream>>>(cursor, NN);
    k_count<<<dim3(EE / 256), dim3(256), 0, stream>>>(dst, cursor);
    k_scan<<<dim3(1), dim3(1024), 0, stream>>>(cursor, csroff, deg);
    k_zero_i<<<dim3(NN / 256), dim3(256), 0, stream>>>(cursor, NN);
    k_fill<<<dim3(EE / 256), dim3(256), 0, stream>>>(src, dst, csroff, cursor, csrsrc);
    k_gstart<<<dim3(1), dim3(128), 0, stream>>>(graph_id, gstart);

    // ---- layer 1: concat input K=128, single pass (128-tile kernel) ----
    k_h2bf_c<<<dim3(NN * 64 / 256), dim3(256), 0, stream>>>(h, Xc128);
    k_agg_small_c<<<dim3(NN), dim3(64), 0, stream>>>(h, Xc128, csroff, csrsrc, deg);
    k_wt2c<<<dim3(HID / 32, 2, 2), dim3(256), 0, stream>>>(Ws1, Wn1, INF, HID, Wt0, 128);
    k_mgemm<<<dim3(HID / 128, NN / 128, 1), dim3(256), 0, stream>>>(
        Xc128, 128, Wt0, 128, 128,
        (const ushort*)nullptr, 0, (const ushort*)nullptr, 0, 0,
        b1, (float*)nullptr, Ybf, HID, 0, p1, p2, 0);
    k_bn_finalize<<<dim3(HID / 256), dim3(256), 0, stream>>>(p1, p2, g1, be1, bnsc, bnsh, MR);
    k_aggbn<<<dim3(NN), dim3(256), 0, stream>>>(Ybf, bnsc, bnsh, X, AggX, csroff, csrsrc, deg);

    // ---- layer 2: 256-tile 8-phase, two-pass K=2048+2048 ----
    k_wt2<<<dim3(HID / 32, HID / 32, 2), dim3(256), 0, stream>>>(Ws2, Wn2, HID, HID, Wt0, Wt1, HID);
    k_mgemm256<<<dim3(HID / 256, NN / 256), dim3(512), 0, stream>>>(
        X, Wt0, AggX, Wt1, HID, HID, b2, Ybf, p1, p2);
    k_bn_finalize<<<dim3(HID / 256), dim3(256), 0, stream>>>(p1, p2, g2, be2, bnsc, bnsh, NN / 256);
    k_aggbn<<<dim3(NN), dim3(256), 0, stream>>>(Ybf, bnsc, bnsh, X, AggX, csroff, csrsrc, deg);

    // ---- layer 3 ----
    k_wt2<<<dim3(HID / 32, HID / 32, 2), dim3(256), 0, stream>>>(Ws3, Wn3, HID, HID, Wt0, Wt1, HID);
    k_mgemm256<<<dim3(HID / 256, NN / 256), dim3(512), 0, stream>>>(
        X, Wt0, AggX, Wt1, HID, HID, b3, Ybf, p1, p2);
    k_bn_finalize<<<dim3(HID / 256), dim3(256), 0, stream>>>(p1, p2, g3, be3, bnsc, bnsh, NN / 256);

    // ---- fused BN + pooling ----
    k_poolbn<<<dim3(HID / 256, 128), dim3(256), 0, stream>>>(Ybf, bnsc, bnsh, gstart, hgbf);

    // ---- MLP head (split-K x4, deterministic two-stage) ----
    k_wt<<<dim3(HID / 32, HID / 32), dim3(256), 0, stream>>>(fc1_w, HID, HID, Wt0, HID);
    k_wt<<<dim3(MID / 32, HID / 32), dim3(256), 0, stream>>>(fc2_w, HID, MID, Wt1, HID);
    k_mgemm<<<dim3(HID / 128, 1, 4), dim3(256), 0, stream>>>(
        hgbf, HID, Wt0, HID, HID / 4,
        (const ushort*)nullptr, 0, (const ushort*)nullptr, 0, 0,
        (const float*)nullptr, partF, (ushort*)nullptr, HID, 0,
        (float*)nullptr, (float*)nullptr, (size_t)128 * HID);
    k_redhead<<<dim3(128 * HID / 256), dim3(256), 0, stream>>>(
        partF, 4, (size_t)128 * HID, fc1_b, HID, x1bf, (float*)nullptr, 128 * HID);
    k_mgemm<<<dim3(MID / 128, 1, 4), dim3(256), 0, stream>>>(
        x1bf, HID, Wt1, HID, HID / 4,
        (const ushort*)nullptr, 0, (const ushort*)nullptr, 0, 0,
        (const float*)nullptr, partF, (ushort*)nullptr, MID, 0,
        (float*)nullptr, (float*)nullptr, (size_t)128 * MID);
    k_redhead<<<dim3(128 * MID / 256), dim3(256), 0, stream>>>(
        partF, 4, (size_t)128 * MID, fc2_b, MID, (ushort*)nullptr, x2f, 128 * MID);
    k_fc3<<<dim3(GG), dim3(256), 0, stream>>>(x2f, fc3_w, fc3_b, out);
}

// Round 3
// 1083.088 us; speedup vs baseline: 1.0321x; 1.0321x over previous
//
#include <hip/hip_runtime.h>
#include <hip/hip_bf16.h>

#define NN   16384
#define EE   65536
#define GG   64
#define INF  63
#define HID  2048
#define MID  1024
#define NCLS 18
#define EPS  1e-5f
#define SLOPE 0.01f
#define MR   (NN / 128)   // 128 block-rows for layer-1 BN partials

typedef unsigned short ushort;
typedef unsigned int uint;

using bf16x8 = __attribute__((ext_vector_type(8))) __bf16;
using f32x4  = __attribute__((ext_vector_type(4))) float;
using f32x16 = __attribute__((ext_vector_type(16))) float;

__device__ __forceinline__ ushort f2us(float x) {
    __hip_bfloat16 b = __float2bfloat16(x);
    return __builtin_bit_cast(ushort, b);
}
__device__ __forceinline__ float us2f(ushort u) {
    return __bfloat162float(__builtin_bit_cast(__hip_bfloat16, u));
}

// async global->LDS, 16B per lane; LDS base wave-uniform, HW adds lane*16
__device__ __forceinline__ void gll16(const ushort* g, ushort* l) {
    __builtin_amdgcn_global_load_lds(
        (const __attribute__((address_space(1))) uint*)g,
        (__attribute__((address_space(3))) uint*)l, 16, 0, 0);
}

// ---------------- utility ----------------

__global__ void k_zero_i(int* __restrict__ p, int n) {
    int i = blockIdx.x * blockDim.x + threadIdx.x;
    if (i < n) p[i] = 0;
}

// ---------------- CSR build (by dst) ----------------

__global__ void k_count(const int* __restrict__ dst, int* __restrict__ cnt) {
    int e = blockIdx.x * blockDim.x + threadIdx.x;
    if (e < EE) atomicAdd(&cnt[dst[e]], 1);
}

__global__ void k_scan(const int* __restrict__ cnt, int* __restrict__ off,
                       float* __restrict__ deg) {
    __shared__ int sh[1024];
    int t = threadIdx.x;
    int base = t * 16;
    int loc[16];
    int s = 0;
#pragma unroll
    for (int i = 0; i < 16; ++i) {
        int c = cnt[base + i];
        loc[i] = s;
        s += c;
        deg[base + i] = (float)c;
    }
    sh[t] = s;
    __syncthreads();
    for (int d = 1; d < 1024; d <<= 1) {
        int v = (t >= d) ? sh[t - d] : 0;
        __syncthreads();
        sh[t] += v;
        __syncthreads();
    }
    int excl = sh[t] - s;
#pragma unroll
    for (int i = 0; i < 16; ++i) off[base + i] = excl + loc[i];
    if (t == 1023) off[NN] = sh[1023];
}

__global__ void k_fill(const int* __restrict__ src, const int* __restrict__ dst,
                       const int* __restrict__ off, int* __restrict__ cur,
                       int* __restrict__ csr_src) {
    int e = blockIdx.x * blockDim.x + threadIdx.x;
    if (e < EE) {
        int d = dst[e];
        int p = atomicAdd(&cur[d], 1);
        csr_src[off[d] + p] = src[e];
    }
}

// ---------------- layer-1 prep (into concat [NN,128]) ----------------

__global__ void k_h2bf_c(const float* __restrict__ h, ushort* __restrict__ Xc) {
    int i = blockIdx.x * 256 + threadIdx.x;  // over NN*64
    int r = i >> 6, c = i & 63;
    Xc[(size_t)r * 128 + c] = (c < INF) ? f2us(h[(size_t)r * INF + c]) : (ushort)0;
}

__global__ void k_agg_small_c(const float* __restrict__ X, ushort* __restrict__ Xc,
                              const int* __restrict__ off, const int* __restrict__ csr_src,
                              const float* __restrict__ deg) {
    int v = blockIdx.x;
    int f = threadIdx.x;  // 64
    float acc = 0.f;
    if (f < INF) {
        int s = off[v], e = off[v + 1];
        for (int i = s; i < e; ++i) acc += X[(size_t)csr_src[i] * INF + f];
        acc /= fmaxf(deg[v], 1.f);
    }
    Xc[(size_t)v * 128 + 64 + f] = f2us(acc);
}

// ---------------- fused BN-apply + aggregation ----------------

__global__ void k_aggbn(const ushort* __restrict__ Ybf,
                        const float* __restrict__ sc8, const float* __restrict__ sh8,
                        ushort* __restrict__ X, ushort* __restrict__ AggX,
                        const int* __restrict__ off, const int* __restrict__ csr_src,
                        const float* __restrict__ deg) {
    int v = blockIdx.x;
    int t = threadIdx.x;
    int c = t * 8;
    float sc[8], sh[8];
    *(float4*)&sc[0] = *(const float4*)&sc8[c];
    *(float4*)&sc[4] = *(const float4*)&sc8[c + 4];
    *(float4*)&sh[0] = *(const float4*)&sh8[c];
    *(float4*)&sh[4] = *(const float4*)&sh8[c + 4];

    // own row
    {
        uint4 u = ((const uint4*)(Ybf + (size_t)v * HID))[t];
        uint wds[4] = {u.x, u.y, u.z, u.w};
        uint o[4];
#pragma unroll
        for (int j = 0; j < 4; ++j) {
            float a = sc[2 * j] * us2f((ushort)(wds[j] & 0xffffu)) + sh[2 * j];
            float b = sc[2 * j + 1] * us2f((ushort)(wds[j] >> 16)) + sh[2 * j + 1];
            a = a > 0.f ? a : SLOPE * a;
            b = b > 0.f ? b : SLOPE * b;
            o[j] = (uint)f2us(a) | ((uint)f2us(b) << 16);
        }
        ((uint4*)(X + (size_t)v * HID))[t] = make_uint4(o[0], o[1], o[2], o[3]);
    }

    // neighbor mean
    int s = off[v], e = off[v + 1];
    float acc[8];
#pragma unroll
    for (int j = 0; j < 8; ++j) acc[j] = 0.f;
    for (int i = s; i < e; ++i) {
        uint4 u = ((const uint4*)(Ybf + (size_t)csr_src[i] * HID))[t];
        uint wds[4] = {u.x, u.y, u.z, u.w};
#pragma unroll
        for (int j = 0; j < 4; ++j) {
            float a = sc[2 * j] * us2f((ushort)(wds[j] & 0xffffu)) + sh[2 * j];
            float b = sc[2 * j + 1] * us2f((ushort)(wds[j] >> 16)) + sh[2 * j + 1];
            acc[2 * j]     += a > 0.f ? a : SLOPE * a;
            acc[2 * j + 1] += b > 0.f ? b : SLOPE * b;
        }
    }
    float inv = 1.f / fmaxf(deg[v], 1.f);
    uint o[4];
#pragma unroll
    for (int j = 0; j < 4; ++j)
        o[j] = (uint)f2us(acc[2 * j] * inv) | ((uint)f2us(acc[2 * j + 1] * inv) << 16);
    ((uint4*)(AggX + (size_t)v * HID))[t] = make_uint4(o[0], o[1], o[2], o[3]);
}

// ---------------- weight transposes ----------------

__global__ void k_wt2(const float* __restrict__ W0, const float* __restrict__ W1,
                      int K, int N, ushort* __restrict__ Wt0, ushort* __restrict__ Wt1,
                      int Kp) {
    const float* W = blockIdx.z ? W1 : W0;
    ushort* Wt = blockIdx.z ? Wt1 : Wt0;
    __shared__ float t[32][33];
    int kb = blockIdx.y * 32, nb = blockIdx.x * 32;
    int tx = threadIdx.x & 31, ty = threadIdx.x >> 5;
#pragma unroll
    for (int i = 0; i < 32; i += 8) {
        int k = kb + ty + i;
        t[ty + i][tx] = (k < K) ? W[(size_t)k * N + nb + tx] : 0.f;
    }
    __syncthreads();
#pragma unroll
    for (int i = 0; i < 32; i += 8)
        Wt[(size_t)(nb + ty + i) * Kp + kb + tx] = f2us(t[tx][ty + i]);
}

__global__ void k_wt2c(const float* __restrict__ W0, const float* __restrict__ W1,
                       int Kw, int N, ushort* __restrict__ Wtc, int KP) {
    const float* W = blockIdx.z ? W1 : W0;
    const int kOff = blockIdx.z ? (KP / 2) : 0;
    __shared__ float t[32][33];
    int kb = blockIdx.y * 32, nb = blockIdx.x * 32;
    int tx = threadIdx.x & 31, ty = threadIdx.x >> 5;
#pragma unroll
    for (int i = 0; i < 32; i += 8) {
        int k = kb + ty + i;
        t[ty + i][tx] = (k < Kw) ? W[(size_t)k * N + nb + tx] : 0.f;
    }
    __syncthreads();
#pragma unroll
    for (int i = 0; i < 32; i += 8)
        Wtc[(size_t)(nb + ty + i) * KP + kOff + kb + tx] = f2us(t[tx][ty + i]);
}

__global__ void k_wt(const float* __restrict__ W, int K, int N,
                     ushort* __restrict__ Wt, int Kp) {
    __shared__ float t[32][33];
    int kb = blockIdx.y * 32, nb = blockIdx.x * 32;
    int tx = threadIdx.x & 31, ty = threadIdx.x >> 5;
#pragma unroll
    for (int i = 0; i < 32; i += 8) {
        int k = kb + ty + i;
        t[ty + i][tx] = (k < K) ? W[(size_t)k * N + nb + tx] : 0.f;
    }
    __syncthreads();
#pragma unroll
    for (int i = 0; i < 32; i += 8)
        Wt[(size_t)(nb + ty + i) * Kp + kb + tx] = f2us(t[tx][ty + i]);
}

// ---------------- MFMA GEMM, 128x128 two-pass (layer-1 + head) ------------

#define BK 64

__global__ __launch_bounds__(256)
void k_mgemm(const ushort* __restrict__ A1, int lda1, const ushort* __restrict__ B1t, int ldb1, int K1,
             const ushort* __restrict__ A2, int lda2, const ushort* __restrict__ B2t, int ldb2, int K2,
             const float* __restrict__ bias, float* __restrict__ Cf, ushort* __restrict__ Cbf,
             int ldc, int fuse_lrelu, float* __restrict__ s1p, float* __restrict__ s2p,
             size_t cStrideZ) {
    __shared__ __align__(16) ushort As[128 * BK];
    __shared__ __align__(16) ushort Bs[128 * BK];
    __shared__ float sb1[4][64];
    __shared__ float sb2[4][64];
    const int tid = threadIdx.x;
    const int lane = tid & 63;
    const int w = tid >> 6;
    const int rowBase = blockIdx.y * 128;
    const int colBase = blockIdx.x * 128;
    const int m0 = (w & 1) * 64;
    const int n0 = (w >> 1) * 64;
    const int z = blockIdx.z;
    A1 += (size_t)z * K1;
    B1t += (size_t)z * K1;
    if (Cf) Cf += (size_t)z * cStrideZ;

    f32x4 acc[4][4];
#pragma unroll
    for (int mi = 0; mi < 4; ++mi)
#pragma unroll
        for (int ni = 0; ni < 4; ++ni) acc[mi][ni] = (f32x4){0.f, 0.f, 0.f, 0.f};

    const int lrow = w * 8 + (lane >> 3);
    const int gc8 = ((lane & 7) ^ (lane >> 3)) * 8;
    const int la = lane & 15, q = lane >> 4;
    const int la7 = lane & 7;

    for (int pass = 0; pass < 2; ++pass) {
        const ushort* A  = pass ? A2 : A1;
        const ushort* Bt = pass ? B2t : B1t;
        const int K   = pass ? K2 : K1;
        const int lda = pass ? lda2 : lda1;
        const int ldb = pass ? ldb2 : ldb1;
        if (A == nullptr) continue;
        const ushort* gA = A + (size_t)(rowBase + lrow) * lda + gc8;
        const ushort* gB = Bt + (size_t)(colBase + lrow) * ldb + gc8;
        for (int kt = 0; kt < K; kt += BK) {
#pragma unroll
            for (int j = 0; j < 4; ++j) {
                gll16(gA + (size_t)(j * 32) * lda + kt, As + j * 2048 + w * 512);
                gll16(gB + (size_t)(j * 32) * ldb + kt, Bs + j * 2048 + w * 512);
            }
            __syncthreads();
#pragma unroll
            for (int kk = 0; kk < 2; ++kk) {
                const int lc8 = ((kk * 4 + q) ^ la7) * 8;
                bf16x8 av[4], bv[4];
#pragma unroll
                for (int mi = 0; mi < 4; ++mi)
                    av[mi] = *(const bf16x8*)&As[(m0 + mi * 16 + la) * BK + lc8];
#pragma unroll
                for (int ni = 0; ni < 4; ++ni)
                    bv[ni] = *(const bf16x8*)&Bs[(n0 + ni * 16 + la) * BK + lc8];
#pragma unroll
                for (int mi = 0; mi < 4; ++mi)
#pragma unroll
                    for (int ni = 0; ni < 4; ++ni)
                        acc[mi][ni] = __builtin_amdgcn_mfma_f32_16x16x32_bf16(
                            av[mi], bv[ni], acc[mi][ni], 0, 0, 0);
            }
            __syncthreads();
        }
    }

#pragma unroll
    for (int mi = 0; mi < 4; ++mi) {
#pragma unroll
        for (int ni = 0; ni < 4; ++ni) {
            const int lc = colBase + n0 + ni * 16 + la;
            const float bv = bias ? bias[lc] : 0.f;
#pragma unroll
            for (int r = 0; r < 4; ++r) {
                const int row = rowBase + m0 + mi * 16 + q * 4 + r;
                float v = acc[mi][ni][r] + bv;
                if (fuse_lrelu) v = v > 0.f ? v : SLOPE * v;
                if (Cbf) Cbf[(size_t)row * ldc + lc] = f2us(v);
                else     Cf[(size_t)row * ldc + lc] = v;
            }
        }
    }

    if (s1p) {
#pragma unroll
        for (int ni = 0; ni < 4; ++ni) {
            const int lc = colBase + n0 + ni * 16 + la;
            const float bv = bias ? bias[lc] : 0.f;
            float t1 = 0.f, t2 = 0.f;
#pragma unroll
            for (int mi = 0; mi < 4; ++mi)
#pragma unroll
                for (int r = 0; r < 4; ++r) {
                    float v = acc[mi][ni][r] + bv;
                    t1 += v;
                    t2 += v * v;
                }
            t1 += __shfl_xor(t1, 16);
            t1 += __shfl_xor(t1, 32);
            t2 += __shfl_xor(t2, 16);
            t2 += __shfl_xor(t2, 32);
            if (q == 0) {
                sb1[w][ni * 16 + la] = t1;
                sb2[w][ni * 16 + la] = t2;
            }
        }
        __syncthreads();
        if (tid < 128) {
            int half = tid >> 6, j = tid & 63;
            float v1 = sb1[2 * half][j] + sb1[2 * half + 1][j];
            float v2 = sb2[2 * half][j] + sb2[2 * half + 1][j];
            size_t o = (size_t)blockIdx.y * ldc + colBase + half * 64 + j;
            s1p[o] = v1;
            s2p[o] = v2;
        }
    }
}

// ---------------- MFMA GEMM, 256x256 pipelined, 32x32x16 (layers 2/3) ------
// C = A1@B1t^T + A2@B2t^T + bias, all ld = HID, K1,K2 multiples of 64.
// 512 thr = 8 waves (2 wm x 4 wn); per-wave 128x64 out as 4 m-tiles x 2
// n-tiles of 32x32; BK=64 (4 k-steps of 16).
// Per-wave tile map (spans BOTH A-halves and BOTH B-halves):
//   mrow(mt) = (mt>>1)*128 + wm*64 + (mt&1)*32 ; ncol(nt) = nt*128 + wn*32
// Fragment-hold schedule, 24 ds_read_b128 per wave per K-tile (minimum):
//   p0: load aL(A0,8) + bL(B0,4) ; mfma aL*bL -> acc[0],acc[2]
//   p1: load aH(A1,8)            ; mfma aH*bL -> acc[4],acc[6]
//   p2: load bH(B1,4)            ; mfma aL*bH -> acc[1],acc[3]
//   p3: (no reads)               ; mfma aH*bH -> acc[5],acc[7]
// First-read stagger {A0:p0,B0:p0,A1:p1,B1:p2} == Round-1 schedule, so the
// stage/vmcnt(6) pipeline proof carries over unchanged:
//   stage: p0->B0(t+1), p1->A1(t+1), p2->B1(t+1), p3->A0(t+2); vmcnt(6) at
//   ends of p0,p1,p3 (never 0 in loop); tail stages clamp to dead regions.
// LDS 16B-chunk XOR swizzle (chunk c of row r holds global chunk c^(r&7));
// 32-row frag reads: each 8-lane group covers all 32 banks once -> 0 conf.

#define STAGEH(kti_, wh_) do {                                                 \
    int _kt = (kti_);                                                          \
    int _ktc = _kt < KT ? _kt : KT - 1;                                        \
    int _pass = (_ktc >= kt1);                                                 \
    int _k0 = (_ktc - (_pass ? kt1 : 0)) << 6;                                 \
    const ushort* _M;                                                          \
    int _h, _slot;                                                             \
    if ((wh_) == 0)      { _M = (_pass ? A2 : A1) + (size_t)rowBase * HID; _h = 0; _slot = 0; } \
    else if ((wh_) == 2) { _M = (_pass ? A2 : A1) + (size_t)rowBase * HID; _h = 1; _slot = 1; } \
    else if ((wh_) == 1) { _M = (_pass ? B2t : B1t) + (size_t)colBase * HID; _h = 0; _slot = 2; } \
    else                 { _M = (_pass ? B2t : B1t) + (size_t)colBase * HID; _h = 1; _slot = 3; } \
    const ushort* _g = _M + (size_t)(_h * 128 + srow) * HID + (size_t)(_k0 + sch); \
    ushort* _l = &lds[_kt & 1][_slot][0] + ldsl;                               \
    gll16(_g, _l);                                                             \
    gll16(_g + (size_t)64 * HID, _l + 4096);                                   \
} while (0)

__global__ __launch_bounds__(512, 2)
void k_mgemm256(const ushort* __restrict__ A1, const ushort* __restrict__ B1t,
                const ushort* __restrict__ A2, const ushort* __restrict__ B2t,
                int K1, int K2,
                const float* __restrict__ bias, ushort* __restrict__ Cbf,
                float* __restrict__ s1p, float* __restrict__ s2p) {
    __shared__ __align__(16) ushort lds[2][4][128 * 64];   // 128 KiB
    __shared__ float sb1[2][256];
    __shared__ float sb2[2][256];

    const int tid  = threadIdx.x;
    const int w    = tid >> 6, lane = tid & 63;
    const int la31 = lane & 31, hi = lane >> 5, la7 = lane & 7;
    const int wm   = w >> 2, wn = w & 3;

    // XCD-aware bijective chunk swizzle (nwg = 8*64 = 512, 512%8==0)
    const int nx  = gridDim.x;                       // 8
    const int lin = blockIdx.y * nx + blockIdx.x;
    const int cpx = (nx * gridDim.y) >> 3;           // 64
    const int swz = (lin & 7) * cpx + (lin >> 3);
    const int bx  = swz & (nx - 1), by = swz / nx;
    const int rowBase = by * 256, colBase = bx * 256;

    const int kt1 = K1 >> 6;
    const int KT  = kt1 + (K2 >> 6);

    // staging lane mapping: row = srow(+64), chunk = tid&7, global chunk XOR'd
    const int srow = tid >> 3;                        // 0..63
    const int sch  = ((tid & 7) ^ (srow & 7)) << 3;   // element offset in k
    const int ldsl = w << 9;                          // wave-uniform (1KiB/wave)

    // reader offsets (elements)
    const int aoff = (wm * 64 + la31) * 64;           // A-half local row base
    const int boff = (wn * 32 + la31) * 64;           // B-half local row base
    int cofs[4];
#pragma unroll
    for (int s_ = 0; s_ < 4; ++s_)
        cofs[s_] = (((s_ * 2 + hi) ^ la7) << 3);      // swizzled k-chunk (elems)

    f32x16 acc[8];
#pragma unroll
    for (int i = 0; i < 8; ++i)
#pragma unroll
        for (int r = 0; r < 16; ++r) acc[i][r] = 0.f;
    bf16x8 aL[2][4], aH[2][4], bL[4], bH[4];

    // prologue: tile0 {A0,B0,A1,B1} + tile1 A0 ; A0(0),B0(0) guaranteed
    STAGEH(0, 0); STAGEH(0, 1); STAGEH(0, 2); STAGEH(0, 3);
    STAGEH(1, 0);
    asm volatile("s_waitcnt vmcnt(6)" ::: "memory");
    __builtin_amdgcn_s_barrier();

    for (int t = 0; t < KT; ++t) {
        const int bf_ = t & 1;
        const ushort* A0h = &lds[bf_][0][0];
        const ushort* A1h = &lds[bf_][1][0];
        const ushort* B0h = &lds[bf_][2][0];
        const ushort* B1h = &lds[bf_][3][0];

        // ---- p0: read aL(A0) + bL(B0); stage B0(t+1); mfma aL*bL ----
#pragma unroll
        for (int m_ = 0; m_ < 2; ++m_)
#pragma unroll
            for (int s_ = 0; s_ < 4; ++s_)
                aL[m_][s_] = *(const bf16x8*)&A0h[aoff + m_ * 2048 + cofs[s_]];
#pragma unroll
        for (int s_ = 0; s_ < 4; ++s_)
            bL[s_] = *(const bf16x8*)&B0h[boff + cofs[s_]];
        STAGEH(t + 1, 1);
        __builtin_amdgcn_s_barrier();
        __builtin_amdgcn_s_setprio(1);
#pragma unroll
        for (int s_ = 0; s_ < 4; ++s_)
#pragma unroll
            for (int m_ = 0; m_ < 2; ++m_)
                acc[m_ * 2] = __builtin_amdgcn_mfma_f32_32x32x16_bf16(
                    aL[m_][s_], bL[s_], acc[m_ * 2], 0, 0, 0);
        __builtin_amdgcn_s_setprio(0);
        asm volatile("s_waitcnt vmcnt(6)" ::: "memory");
        __builtin_amdgcn_s_barrier();

        // ---- p1: read aH(A1); stage A1(t+1); mfma aH*bL ----
#pragma unroll
        for (int m_ = 0; m_ < 2; ++m_)
#pragma unroll
            for (int s_ = 0; s_ < 4; ++s_)
                aH[m_][s_] = *(const bf16x8*)&A1h[aoff + m_ * 2048 + cofs[s_]];
        STAGEH(t + 1, 2);
        __builtin_amdgcn_s_barrier();
        __builtin_amdgcn_s_setprio(1);
#pragma unroll
        for (int s_ = 0; s_ < 4; ++s_)
#pragma unroll
            for (int m_ = 0; m_ < 2; ++m_)
                acc[4 + m_ * 2] = __builtin_amdgcn_mfma_f32_32x32x16_bf16(
                    aH[m_][s_], bL[s_], acc[4 + m_ * 2], 0, 0, 0);
        __builtin_amdgcn_s_setprio(0);
        asm volatile("s_waitcnt vmcnt(6)" ::: "memory");
        __builtin_amdgcn_s_barrier();

        // ---- p2: read bH(B1); stage B1(t+1); mfma aL*bH ----
#pragma unroll
        for (int s_ = 0; s_ < 4; ++s_)
            bH[s_] = *(const bf16x8*)&B1h[boff + cofs[s_]];
        STAGEH(t + 1, 3);
        __builtin_amdgcn_s_barrier();
        __builtin_amdgcn_s_setprio(1);
#pragma unroll
        for (int s_ = 0; s_ < 4; ++s_)
#pragma unroll
            for (int m_ = 0; m_ < 2; ++m_)
                acc[1 + m_ * 2] = __builtin_amdgcn_mfma_f32_32x32x16_bf16(
                    aL[m_][s_], bH[s_], acc[1 + m_ * 2], 0, 0, 0);
        __builtin_amdgcn_s_setprio(0);
        __builtin_amdgcn_s_barrier();

        // ---- p3: no reads; stage A0(t+2); mfma aH*bH ----
        STAGEH(t + 2, 0);
        __builtin_amdgcn_s_barrier();
        __builtin_amdgcn_s_setprio(1);
#pragma unroll
        for (int s_ = 0; s_ < 4; ++s_)
#pragma unroll
            for (int m_ = 0; m_ < 2; ++m_)
                acc[5 + m_ * 2] = __builtin_amdgcn_mfma_f32_32x32x16_bf16(
                    aH[m_][s_], bH[s_], acc[5 + m_ * 2], 0, 0, 0);
        __builtin_amdgcn_s_setprio(0);
        asm volatile("s_waitcnt vmcnt(6)" ::: "memory");
        __builtin_amdgcn_s_barrier();
    }

    __syncthreads();   // drain everything before epilogue

    // C store (32x32 C/D: col = lane&31, row = (reg&3) + 8*(reg>>2) + 4*hi)
#pragma unroll
    for (int mt = 0; mt < 4; ++mt) {
        const int rb = rowBase + (mt >> 1) * 128 + wm * 64 + (mt & 1) * 32 + hi * 4;
#pragma unroll
        for (int nt = 0; nt < 2; ++nt) {
            const int col = colBase + nt * 128 + wn * 32 + la31;
            const float bv = bias[col];
#pragma unroll
            for (int r = 0; r < 16; ++r) {
                const int row = rb + (r & 3) + (r >> 2) * 8;
                Cbf[(size_t)row * HID + col] = f2us(acc[mt * 2 + nt][r] + bv);
            }
        }
    }

    // fused BN partial stats (pre-activation, fp32 exact)
#pragma unroll
    for (int nt = 0; nt < 2; ++nt) {
        const int cl = nt * 128 + wn * 32 + la31;
        const float bv = bias[colBase + cl];
        float t1 = 0.f, t2 = 0.f;
#pragma unroll
        for (int mt = 0; mt < 4; ++mt)
#pragma unroll
            for (int r = 0; r < 16; ++r) {
                float v = acc[mt * 2 + nt][r] + bv;
                t1 += v;
                t2 += v * v;
            }
        t1 += __shfl_xor(t1, 32);
        t2 += __shfl_xor(t2, 32);
        if (hi == 0) { sb1[wm][cl] = t1; sb2[wm][cl] = t2; }
    }
    __syncthreads();
    if (tid < 256) {
        size_t o = (size_t)by * HID + colBase + tid;
        s1p[o] = sb1[0][tid] + sb1[1][tid];
        s2p[o] = sb2[0][tid] + sb2[1][tid];
    }
}

// ---------------- BatchNorm finalize ----------------

__global__ void k_bn_finalize(const float* __restrict__ p1, const float* __restrict__ p2,
                              const float* __restrict__ gamma, const float* __restrict__ beta,
                              float* __restrict__ scale, float* __restrict__ shift, int nrb) {
    int c = blockIdx.x * 256 + threadIdx.x;
    if (c >= HID) return;
    float s1 = 0.f, s2 = 0.f;
    for (int rb = 0; rb < nrb; ++rb) {
        s1 += p1[(size_t)rb * HID + c];
        s2 += p2[(size_t)rb * HID + c];
    }
    float mean = s1 * (1.f / (float)NN);
    float var = s2 * (1.f / (float)NN) - mean * mean;
    var = fmaxf(var, 0.f);
    float sc = gamma[c] * rsqrtf(var + EPS);
    scale[c] = sc;
    shift[c] = beta[c] - mean * sc;
}

// ---------------- fused BN + pooling ----------------

__global__ void k_poolbn(const ushort* __restrict__ Ybf,
                         const float* __restrict__ scale, const float* __restrict__ shift,
                         const int* __restrict__ gstart, ushort* __restrict__ hgbf) {
    int g = blockIdx.y;
    int col = blockIdx.x * 256 + threadIdx.x;
    if (g >= GG) {
        hgbf[(size_t)g * HID + col] = 0;
        return;
    }
    int s = gstart[g], e = gstart[g + 1];
    float sc = scale[col], sh = shift[col];
    float acc = 0.f;
    for (int n = s; n < e; ++n) {
        float v = sc * us2f(Ybf[(size_t)n * HID + col]) + sh;
        acc += v > 0.f ? v : SLOPE * v;
    }
    hgbf[(size_t)g * HID + col] = f2us(acc / fmaxf((float)(e - s), 1.f));
}

__global__ void k_gstart(const int* __restrict__ gid, int* __restrict__ gstart) {
    int g = threadIdx.x;
    if (g > GG) return;
    int lo = 0, hi = NN;
    while (lo < hi) {
        int mid = (lo + hi) >> 1;
        if (gid[mid] < g) lo = mid + 1; else hi = mid;
    }
    gstart[g] = lo;
}

// ---------------- split-K reduce for head GEMMs ----------------

__global__ void k_redhead(const float* __restrict__ part, int P, size_t strideZ,
                          const float* __restrict__ bias, int ldc,
                          ushort* __restrict__ obf, float* __restrict__ of, int n) {
    int i = blockIdx.x * 256 + threadIdx.x;
    if (i >= n) return;
    float s = 0.f;
    for (int p = 0; p < P; ++p) s += part[(size_t)p * strideZ + i];
    s += bias[i % ldc];
    s = s > 0.f ? s : SLOPE * s;
    if (obf) obf[i] = f2us(s);
    else     of[i] = s;
}

__global__ void k_fc3(const float* __restrict__ x2, const float* __restrict__ W,
                      const float* __restrict__ b, float* __restrict__ out) {
    int g = blockIdx.x;
    int tid = threadIdx.x;
    float part[NCLS];
#pragma unroll
    for (int c = 0; c < NCLS; ++c) part[c] = 0.f;
    for (int k = tid; k < MID; k += 256) {
        float x = x2[(size_t)g * MID + k];
        const float* wr = W + (size_t)k * NCLS;
#pragma unroll
        for (int c = 0; c < NCLS; ++c) part[c] += x * wr[c];
    }
    __shared__ float red[4][NCLS];
    int lane = tid & 63, w = tid >> 6;
#pragma unroll
    for (int c = 0; c < NCLS; ++c) {
        float v = part[c];
        for (int o = 32; o > 0; o >>= 1) v += __shfl_down(v, o, 64);
        if (lane == 0) red[w][c] = v;
    }
    __syncthreads();
    if (tid < NCLS)
        out[(size_t)g * NCLS + tid] = red[0][tid] + red[1][tid] + red[2][tid] + red[3][tid] + b[tid];
}

// ---------------- launcher ----------------

extern "C" void kernel_launch(void* const* d_in, const int* in_sizes, int n_in,
                              void* d_out, int out_size, void* d_ws, size_t ws_size,
                              hipStream_t stream) {
    const float* h        = (const float*)d_in[0];
    const int*   src      = (const int*)d_in[1];
    const int*   dst      = (const int*)d_in[2];
    const int*   graph_id = (const int*)d_in[3];
    const float* Ws1 = (const float*)d_in[4];
    const float* Wn1 = (const float*)d_in[5];
    const float* b1  = (const float*)d_in[6];
    const float* Ws2 = (const float*)d_in[7];
    const float* Wn2 = (const float*)d_in[8];
    const float* b2  = (const float*)d_in[9];
    const float* Ws3 = (const float*)d_in[10];
    const float* Wn3 = (const float*)d_in[11];
    const float* b3  = (const float*)d_in[12];
    const float* g1  = (const float*)d_in[13];
    const float* be1 = (const float*)d_in[14];
    const float* g2  = (const float*)d_in[15];
    const float* be2 = (const float*)d_in[16];
    const float* g3  = (const float*)d_in[17];
    const float* be3 = (const float*)d_in[18];
    const float* fc1_w = (const float*)d_in[19];
    const float* fc1_b = (const float*)d_in[20];
    const float* fc2_w = (const float*)d_in[21];
    const float* fc2_b = (const float*)d_in[22];
    const float* fc3_w = (const float*)d_in[23];
    const float* fc3_b = (const float*)d_in[24];
    float* out = (float*)d_out;

    size_t off_b = 0;
    auto alloc = [&](size_t bytes) -> void* {
        void* p = (char*)d_ws + off_b;
        off_b += (bytes + 255) & ~(size_t)255;
        return p;
    };
    ushort* Wt0    = (ushort*)alloc((size_t)2 * HID * HID * 2);  // 16 MiB (2 slots)
    ushort* Wt1    = Wt0 + (size_t)HID * HID;
    ushort* X      = (ushort*)alloc((size_t)NN * HID * 2);       // 64 MiB
    ushort* AggX   = (ushort*)alloc((size_t)NN * HID * 2);       // 64 MiB
    ushort* Ybf    = (ushort*)alloc((size_t)NN * HID * 2);       // 64 MiB
    float*  deg    = (float*)alloc((size_t)NN * 4);
    int*    csroff = (int*)alloc((size_t)(NN + 1) * 4);
    int*    cursor = (int*)alloc((size_t)NN * 4);
    int*    csrsrc = (int*)alloc((size_t)EE * 4);
    float*  p1     = (float*)alloc((size_t)MR * HID * 4);        // 1 MiB
    float*  p2     = (float*)alloc((size_t)MR * HID * 4);        // 1 MiB
    float*  bnsc   = (float*)alloc((size_t)HID * 4);
    float*  bnsh   = (float*)alloc((size_t)HID * 4);
    int*    gstart = (int*)alloc((size_t)(GG + 1) * 4);

    ushort* Xc128 = X;
    ushort* hgbf  = AggX;
    ushort* x1bf  = AggX + (size_t)128 * HID;
    float*  x2f   = (float*)(AggX + (size_t)2 * 128 * HID);
    float*  partF = (float*)(AggX + (size_t)3 * 128 * HID);

    // ---- CSR build ----
    k_zero_i<<<dim3(NN / 256), dim3(256), 0, stream>>>(cursor, NN);
    k_count<<<dim3(EE / 256), dim3(256), 0, stream>>>(dst, cursor);
    k_scan<<<dim3(1), dim3(1024), 0, stream>>>(cursor, csroff, deg);
    k_zero_i<<<dim3(NN / 256), dim3(256), 0, stream>>>(cursor, NN);
    k_fill<<<dim3(EE / 256), dim3(256), 0, stream>>>(src, dst, csroff, cursor, csrsrc);
    k_gstart<<<dim3(1), dim3(128), 0, stream>>>(graph_id, gstart);

    // ---- layer 1: concat input K=128, single pass (128-tile kernel) ----
    k_h2bf_c<<<dim3(NN * 64 / 256), dim3(256), 0, stream>>>(h, Xc128);
    k_agg_small_c<<<dim3(NN), dim3(64), 0, stream>>>(h, Xc128, csroff, csrsrc, deg);
    k_wt2c<<<dim3(HID / 32, 2, 2), dim3(256), 0, stream>>>(Ws1, Wn1, INF, HID, Wt0, 128);
    k_mgemm<<<dim3(HID / 128, NN / 128, 1), dim3(256), 0, stream>>>(
        Xc128, 128, Wt0, 128, 128,
        (const ushort*)nullptr, 0, (const ushort*)nullptr, 0, 0,
        b1, (float*)nullptr, Ybf, HID, 0, p1, p2, 0);
    k_bn_finalize<<<dim3(HID / 256), dim3(256), 0, stream>>>(p1, p2, g1, be1, bnsc, bnsh, MR);
    k_aggbn<<<dim3(NN), dim3(256), 0, stream>>>(Ybf, bnsc, bnsh, X, AggX, csroff, csrsrc, deg);

    // ---- layer 2: 256-tile 32x32 pipelined, two-pass K=2048+2048 ----
    k_wt2<<<dim3(HID / 32, HID / 32, 2), dim3(256), 0, stream>>>(Ws2, Wn2, HID, HID, Wt0, Wt1, HID);
    k_mgemm256<<<dim3(HID / 256, NN / 256), dim3(512), 0, stream>>>(
        X, Wt0, AggX, Wt1, HID, HID, b2, Ybf, p1, p2);
    k_bn_finalize<<<dim3(HID / 256), dim3(256), 0, stream>>>(p1, p2, g2, be2, bnsc, bnsh, NN / 256);
    k_aggbn<<<dim3(NN), dim3(256), 0, stream>>>(Ybf, bnsc, bnsh, X, AggX, csroff, csrsrc, deg);

    // ---- layer 3 ----
    k_wt2<<<dim3(HID / 32, HID / 32, 2), dim3(256), 0, stream>>>(Ws3, Wn3, HID, HID, Wt0, Wt1, HID);
    k_mgemm256<<<dim3(HID / 256, NN / 256), dim3(512), 0, stream>>>(
        X, Wt0, AggX, Wt1, HID, HID, b3, Ybf, p1, p2);
    k_bn_finalize<<<dim3(HID / 256), dim3(256), 0, stream>>>(p1, p2, g3, be3, bnsc, bnsh, NN / 256);

    // ---- fused BN + pooling ----
    k_poolbn<<<dim3(HID / 256, 128), dim3(256), 0, stream>>>(Ybf, bnsc, bnsh, gstart, hgbf);

    // ---- MLP head (split-K x4, deterministic two-stage) ----
    k_wt<<<dim3(HID / 32, HID / 32), dim3(256), 0, stream>>>(fc1_w, HID, HID, Wt0, HID);
    k_wt<<<dim3(MID / 32, HID / 32), dim3(256), 0, stream>>>(fc2_w, HID, MID, Wt1, HID);
    k_mgemm<<<dim3(HID / 128, 1, 4), dim3(256), 0, stream>>>(
        hgbf, HID, Wt0, HID, HID / 4,
        (const ushort*)nullptr, 0, (const ushort*)nullptr, 0, 0,
        (const float*)nullptr, partF, (ushort*)nullptr, HID, 0,
        (float*)nullptr, (float*)nullptr, (size_t)128 * HID);
    k_redhead<<<dim3(128 * HID / 256), dim3(256), 0, stream>>>(
        partF, 4, (size_t)128 * HID, fc1_b, HID, x1bf, (float*)nullptr, 128 * HID);
    k_mgemm<<<dim3(MID / 128, 1, 4), dim3(256), 0, stream>>>(
        x1bf, HID, Wt1, HID, HID / 4,
        (const ushort*)nullptr, 0, (const ushort*)nullptr, 0, 0,
        (const float*)nullptr, partF, (ushort*)nullptr, MID, 0,
        (float*)nullptr, (float*)nullptr, (size_t)128 * MID);
    k_redhead<<<dim3(128 * MID / 256), dim3(256), 0, stream>>>(
        partF, 4, (size_t)128 * MID, fc2_b, MID, (ushort*)nullptr, x2f, 128 * MID);
    k_fc3<<<dim3(GG), dim3(256), 0, stream>>>(x2f, fc3_w, fc3_b, out);
}

// Round 4
// 1017.168 us; speedup vs baseline: 1.0990x; 1.0648x over previous
//
#include <hip/hip_runtime.h>
#include <hip/hip_bf16.h>

#define NN   16384
#define EE   65536
#define GG   64
#define INF  63
#define HID  2048
#define MID  1024
#define NCLS 18
#define EPS  1e-5f
#define SLOPE 0.01f
#define MR   (NN / 128)   // 128 block-rows for layer-1 BN partials

typedef unsigned short ushort;
typedef unsigned int uint;

using bf16x8 = __attribute__((ext_vector_type(8))) __bf16;
using f32x4  = __attribute__((ext_vector_type(4))) float;

__device__ __forceinline__ ushort f2us(float x) {
    __hip_bfloat16 b = __float2bfloat16(x);
    return __builtin_bit_cast(ushort, b);
}
__device__ __forceinline__ float us2f(ushort u) {
    return __bfloat162float(__builtin_bit_cast(__hip_bfloat16, u));
}

// async global->LDS, 16B per lane; LDS base wave-uniform, HW adds lane*16
__device__ __forceinline__ void gll16(const ushort* g, ushort* l) {
    __builtin_amdgcn_global_load_lds(
        (const __attribute__((address_space(1))) uint*)g,
        (__attribute__((address_space(3))) uint*)l, 16, 0, 0);
}

// ---------------- utility ----------------

__global__ void k_zero_i(int* __restrict__ p, int n) {
    int i = blockIdx.x * blockDim.x + threadIdx.x;
    if (i < n) p[i] = 0;
}

// ---------------- CSR build (by dst) ----------------

__global__ void k_count(const int* __restrict__ dst, int* __restrict__ cnt) {
    int e = blockIdx.x * blockDim.x + threadIdx.x;
    if (e < EE) atomicAdd(&cnt[dst[e]], 1);
}

__global__ void k_scan(const int* __restrict__ cnt, int* __restrict__ off,
                       float* __restrict__ deg) {
    __shared__ int sh[1024];
    int t = threadIdx.x;
    int base = t * 16;
    int loc[16];
    int s = 0;
#pragma unroll
    for (int i = 0; i < 16; ++i) {
        int c = cnt[base + i];
        loc[i] = s;
        s += c;
        deg[base + i] = (float)c;
    }
    sh[t] = s;
    __syncthreads();
    for (int d = 1; d < 1024; d <<= 1) {
        int v = (t >= d) ? sh[t - d] : 0;
        __syncthreads();
        sh[t] += v;
        __syncthreads();
    }
    int excl = sh[t] - s;
#pragma unroll
    for (int i = 0; i < 16; ++i) off[base + i] = excl + loc[i];
    if (t == 1023) off[NN] = sh[1023];
}

__global__ void k_fill(const int* __restrict__ src, const int* __restrict__ dst,
                       const int* __restrict__ off, int* __restrict__ cur,
                       int* __restrict__ csr_src) {
    int e = blockIdx.x * blockDim.x + threadIdx.x;
    if (e < EE) {
        int d = dst[e];
        int p = atomicAdd(&cur[d], 1);
        csr_src[off[d] + p] = src[e];
    }
}

// ---------------- layer-1 prep (into concat [NN,128]) ----------------

__global__ void k_h2bf_c(const float* __restrict__ h, ushort* __restrict__ Xc) {
    int i = blockIdx.x * 256 + threadIdx.x;  // over NN*64
    int r = i >> 6, c = i & 63;
    Xc[(size_t)r * 128 + c] = (c < INF) ? f2us(h[(size_t)r * INF + c]) : (ushort)0;
}

__global__ void k_agg_small_c(const float* __restrict__ X, ushort* __restrict__ Xc,
                              const int* __restrict__ off, const int* __restrict__ csr_src,
                              const float* __restrict__ deg) {
    int v = blockIdx.x;
    int f = threadIdx.x;  // 64
    float acc = 0.f;
    if (f < INF) {
        int s = off[v], e = off[v + 1];
        for (int i = s; i < e; ++i) acc += X[(size_t)csr_src[i] * INF + f];
        acc /= fmaxf(deg[v], 1.f);
    }
    Xc[(size_t)v * 128 + 64 + f] = f2us(acc);
}

// ---------------- fused BN-apply + aggregation ----------------

__global__ void k_aggbn(const ushort* __restrict__ Ybf,
                        const float* __restrict__ sc8, const float* __restrict__ sh8,
                        ushort* __restrict__ X, ushort* __restrict__ AggX,
                        const int* __restrict__ off, const int* __restrict__ csr_src,
                        const float* __restrict__ deg) {
    int v = blockIdx.x;
    int t = threadIdx.x;
    int c = t * 8;
    float sc[8], sh[8];
    *(float4*)&sc[0] = *(const float4*)&sc8[c];
    *(float4*)&sc[4] = *(const float4*)&sc8[c + 4];
    *(float4*)&sh[0] = *(const float4*)&sh8[c];
    *(float4*)&sh[4] = *(const float4*)&sh8[c + 4];

    // own row
    {
        uint4 u = ((const uint4*)(Ybf + (size_t)v * HID))[t];
        uint wds[4] = {u.x, u.y, u.z, u.w};
        uint o[4];
#pragma unroll
        for (int j = 0; j < 4; ++j) {
            float a = sc[2 * j] * us2f((ushort)(wds[j] & 0xffffu)) + sh[2 * j];
            float b = sc[2 * j + 1] * us2f((ushort)(wds[j] >> 16)) + sh[2 * j + 1];
            a = a > 0.f ? a : SLOPE * a;
            b = b > 0.f ? b : SLOPE * b;
            o[j] = (uint)f2us(a) | ((uint)f2us(b) << 16);
        }
        ((uint4*)(X + (size_t)v * HID))[t] = make_uint4(o[0], o[1], o[2], o[3]);
    }

    // neighbor mean
    int s = off[v], e = off[v + 1];
    float acc[8];
#pragma unroll
    for (int j = 0; j < 8; ++j) acc[j] = 0.f;
    for (int i = s; i < e; ++i) {
        uint4 u = ((const uint4*)(Ybf + (size_t)csr_src[i] * HID))[t];
        uint wds[4] = {u.x, u.y, u.z, u.w};
#pragma unroll
        for (int j = 0; j < 4; ++j) {
            float a = sc[2 * j] * us2f((ushort)(wds[j] & 0xffffu)) + sh[2 * j];
            float b = sc[2 * j + 1] * us2f((ushort)(wds[j] >> 16)) + sh[2 * j + 1];
            acc[2 * j]     += a > 0.f ? a : SLOPE * a;
            acc[2 * j + 1] += b > 0.f ? b : SLOPE * b;
        }
    }
    float inv = 1.f / fmaxf(deg[v], 1.f);
    uint o[4];
#pragma unroll
    for (int j = 0; j < 4; ++j)
        o[j] = (uint)f2us(acc[2 * j] * inv) | ((uint)f2us(acc[2 * j + 1] * inv) << 16);
    ((uint4*)(AggX + (size_t)v * HID))[t] = make_uint4(o[0], o[1], o[2], o[3]);
}

// ---------------- weight transposes ----------------

__global__ void k_wt2(const float* __restrict__ W0, const float* __restrict__ W1,
                      int K, int N, ushort* __restrict__ Wt0, ushort* __restrict__ Wt1,
                      int Kp) {
    const float* W = blockIdx.z ? W1 : W0;
    ushort* Wt = blockIdx.z ? Wt1 : Wt0;
    __shared__ float t[32][33];
    int kb = blockIdx.y * 32, nb = blockIdx.x * 32;
    int tx = threadIdx.x & 31, ty = threadIdx.x >> 5;
#pragma unroll
    for (int i = 0; i < 32; i += 8) {
        int k = kb + ty + i;
        t[ty + i][tx] = (k < K) ? W[(size_t)k * N + nb + tx] : 0.f;
    }
    __syncthreads();
#pragma unroll
    for (int i = 0; i < 32; i += 8)
        Wt[(size_t)(nb + ty + i) * Kp + kb + tx] = f2us(t[tx][ty + i]);
}

__global__ void k_wt2c(const float* __restrict__ W0, const float* __restrict__ W1,
                       int Kw, int N, ushort* __restrict__ Wtc, int KP) {
    const float* W = blockIdx.z ? W1 : W0;
    const int kOff = blockIdx.z ? (KP / 2) : 0;
    __shared__ float t[32][33];
    int kb = blockIdx.y * 32, nb = blockIdx.x * 32;
    int tx = threadIdx.x & 31, ty = threadIdx.x >> 5;
#pragma unroll
    for (int i = 0; i < 32; i += 8) {
        int k = kb + ty + i;
        t[ty + i][tx] = (k < Kw) ? W[(size_t)k * N + nb + tx] : 0.f;
    }
    __syncthreads();
#pragma unroll
    for (int i = 0; i < 32; i += 8)
        Wtc[(size_t)(nb + ty + i) * KP + kOff + kb + tx] = f2us(t[tx][ty + i]);
}

__global__ void k_wt(const float* __restrict__ W, int K, int N,
                     ushort* __restrict__ Wt, int Kp) {
    __shared__ float t[32][33];
    int kb = blockIdx.y * 32, nb = blockIdx.x * 32;
    int tx = threadIdx.x & 31, ty = threadIdx.x >> 5;
#pragma unroll
    for (int i = 0; i < 32; i += 8) {
        int k = kb + ty + i;
        t[ty + i][tx] = (k < K) ? W[(size_t)k * N + nb + tx] : 0.f;
    }
    __syncthreads();
#pragma unroll
    for (int i = 0; i < 32; i += 8)
        Wt[(size_t)(nb + ty + i) * Kp + kb + tx] = f2us(t[tx][ty + i]);
}

// ---------------- MFMA GEMM, 128x128 two-pass (layer-1 + head) ------------

#define BK 64

__global__ __launch_bounds__(256)
void k_mgemm(const ushort* __restrict__ A1, int lda1, const ushort* __restrict__ B1t, int ldb1, int K1,
             const ushort* __restrict__ A2, int lda2, const ushort* __restrict__ B2t, int ldb2, int K2,
             const float* __restrict__ bias, float* __restrict__ Cf, ushort* __restrict__ Cbf,
             int ldc, int fuse_lrelu, float* __restrict__ s1p, float* __restrict__ s2p,
             size_t cStrideZ) {
    __shared__ __align__(16) ushort As[128 * BK];
    __shared__ __align__(16) ushort Bs[128 * BK];
    __shared__ float sb1[4][64];
    __shared__ float sb2[4][64];
    const int tid = threadIdx.x;
    const int lane = tid & 63;
    const int w = tid >> 6;
    const int rowBase = blockIdx.y * 128;
    const int colBase = blockIdx.x * 128;
    const int m0 = (w & 1) * 64;
    const int n0 = (w >> 1) * 64;
    const int z = blockIdx.z;
    A1 += (size_t)z * K1;
    B1t += (size_t)z * K1;
    if (Cf) Cf += (size_t)z * cStrideZ;

    f32x4 acc[4][4];
#pragma unroll
    for (int mi = 0; mi < 4; ++mi)
#pragma unroll
        for (int ni = 0; ni < 4; ++ni) acc[mi][ni] = (f32x4){0.f, 0.f, 0.f, 0.f};

    const int lrow = w * 8 + (lane >> 3);
    const int gc8 = ((lane & 7) ^ (lane >> 3)) * 8;
    const int la = lane & 15, q = lane >> 4;
    const int la7 = lane & 7;

    for (int pass = 0; pass < 2; ++pass) {
        const ushort* A  = pass ? A2 : A1;
        const ushort* Bt = pass ? B2t : B1t;
        const int K   = pass ? K2 : K1;
        const int lda = pass ? lda2 : lda1;
        const int ldb = pass ? ldb2 : ldb1;
        if (A == nullptr) continue;
        const ushort* gA = A + (size_t)(rowBase + lrow) * lda + gc8;
        const ushort* gB = Bt + (size_t)(colBase + lrow) * ldb + gc8;
        for (int kt = 0; kt < K; kt += BK) {
#pragma unroll
            for (int j = 0; j < 4; ++j) {
                gll16(gA + (size_t)(j * 32) * lda + kt, As + j * 2048 + w * 512);
                gll16(gB + (size_t)(j * 32) * ldb + kt, Bs + j * 2048 + w * 512);
            }
            __syncthreads();
#pragma unroll
            for (int kk = 0; kk < 2; ++kk) {
                const int lc8 = ((kk * 4 + q) ^ la7) * 8;
                bf16x8 av[4], bv[4];
#pragma unroll
                for (int mi = 0; mi < 4; ++mi)
                    av[mi] = *(const bf16x8*)&As[(m0 + mi * 16 + la) * BK + lc8];
#pragma unroll
                for (int ni = 0; ni < 4; ++ni)
                    bv[ni] = *(const bf16x8*)&Bs[(n0 + ni * 16 + la) * BK + lc8];
#pragma unroll
                for (int mi = 0; mi < 4; ++mi)
#pragma unroll
                    for (int ni = 0; ni < 4; ++ni)
                        acc[mi][ni] = __builtin_amdgcn_mfma_f32_16x16x32_bf16(
                            av[mi], bv[ni], acc[mi][ni], 0, 0, 0);
            }
            __syncthreads();
        }
    }

#pragma unroll
    for (int mi = 0; mi < 4; ++mi) {
#pragma unroll
        for (int ni = 0; ni < 4; ++ni) {
            const int lc = colBase + n0 + ni * 16 + la;
            const float bv = bias ? bias[lc] : 0.f;
#pragma unroll
            for (int r = 0; r < 4; ++r) {
                const int row = rowBase + m0 + mi * 16 + q * 4 + r;
                float v = acc[mi][ni][r] + bv;
                if (fuse_lrelu) v = v > 0.f ? v : SLOPE * v;
                if (Cbf) Cbf[(size_t)row * ldc + lc] = f2us(v);
                else     Cf[(size_t)row * ldc + lc] = v;
            }
        }
    }

    if (s1p) {
#pragma unroll
        for (int ni = 0; ni < 4; ++ni) {
            const int lc = colBase + n0 + ni * 16 + la;
            const float bv = bias ? bias[lc] : 0.f;
            float t1 = 0.f, t2 = 0.f;
#pragma unroll
            for (int mi = 0; mi < 4; ++mi)
#pragma unroll
                for (int r = 0; r < 4; ++r) {
                    float v = acc[mi][ni][r] + bv;
                    t1 += v;
                    t2 += v * v;
                }
            t1 += __shfl_xor(t1, 16);
            t1 += __shfl_xor(t1, 32);
            t2 += __shfl_xor(t2, 16);
            t2 += __shfl_xor(t2, 32);
            if (q == 0) {
                sb1[w][ni * 16 + la] = t1;
                sb2[w][ni * 16 + la] = t2;
            }
        }
        __syncthreads();
        if (tid < 128) {
            int half = tid >> 6, j = tid & 63;
            float v1 = sb1[2 * half][j] + sb1[2 * half + 1][j];
            float v2 = sb2[2 * half][j] + sb2[2 * half + 1][j];
            size_t o = (size_t)blockIdx.y * ldc + colBase + half * 64 + j;
            s1p[o] = v1;
            s2p[o] = v2;
        }
    }
}

// ---------------- MFMA GEMM, 256x256 pipelined, 16x16x32 + frag-hold ------
// (layers 2/3)  C = A1@B1t^T + A2@B2t^T + bias, ld = HID, K1,K2 mult of 64.
// 512 thr = 8 waves (2 wm x 4 wn); per-wave 128x64 out as acc[8][4] of
// 16x16 tiles (Round-1-verified mapping); BK=64 (2 kk-chunks of 32).
// Fragment-hold, 24 ds_read_b128 per wave per K-tile (vs 40 in Round 1),
// with Round-1's PROVEN 0-conflict read addressing (rows via lane&15):
//   p0: read aL(A0,8) + bL(B0,4) ; mfma aL*bL -> acc[0..3][0..1]
//   p1: read aH(A1,8)            ; mfma aH*bL -> acc[4..7][0..1]
//   p2: read bH(B1,4)            ; mfma aL*bH -> acc[0..3][2..3]  (aL held)
//   p3: (no reads)               ; mfma aH*bH -> acc[4..7][2..3]
// First-read stagger {A0:p0,B0:p0,A1:p1,B1:p2} == Round-1 schedule; the
// stage/vmcnt(6) pipeline proof carries over unchanged:
//   stage: p0->B0(t+1), p1->A1(t+1), p2->B1(t+1), p3->A0(t+2); vmcnt(6) at
//   ends of p0,p1,p3 (never 0 in loop); tail stages clamp to dead regions.
// LDS 16B-chunk XOR swizzle (chunk c of row r holds global chunk c^(r&7)).

#define STAGEH(kti_, wh_) do {                                                 \
    int _kt = (kti_);                                                          \
    int _ktc = _kt < KT ? _kt : KT - 1;                                        \
    int _pass = (_ktc >= kt1);                                                 \
    int _k0 = (_ktc - (_pass ? kt1 : 0)) << 6;                                 \
    const ushort* _M;                                                          \
    int _h, _slot;                                                             \
    if ((wh_) == 0)      { _M = (_pass ? A2 : A1) + (size_t)rowBase * HID; _h = 0; _slot = 0; } \
    else if ((wh_) == 2) { _M = (_pass ? A2 : A1) + (size_t)rowBase * HID; _h = 1; _slot = 1; } \
    else if ((wh_) == 1) { _M = (_pass ? B2t : B1t) + (size_t)colBase * HID; _h = 0; _slot = 2; } \
    else                 { _M = (_pass ? B2t : B1t) + (size_t)colBase * HID; _h = 1; _slot = 3; } \
    const ushort* _g = _M + (size_t)(_h * 128 + srow) * HID + (size_t)(_k0 + sch); \
    ushort* _l = &lds[_kt & 1][_slot][0] + ldsl;                               \
    gll16(_g, _l);                                                             \
    gll16(_g + (size_t)64 * HID, _l + 4096);                                   \
} while (0)

__global__ __launch_bounds__(512, 2)
void k_mgemm256(const ushort* __restrict__ A1, const ushort* __restrict__ B1t,
                const ushort* __restrict__ A2, const ushort* __restrict__ B2t,
                int K1, int K2,
                const float* __restrict__ bias, ushort* __restrict__ Cbf,
                float* __restrict__ s1p, float* __restrict__ s2p) {
    __shared__ __align__(16) ushort lds[2][4][128 * 64];   // 128 KiB
    __shared__ float sb1[2][256];
    __shared__ float sb2[2][256];

    const int tid  = threadIdx.x;
    const int w    = tid >> 6, lane = tid & 63;
    const int la   = lane & 15, q = lane >> 4, la7 = lane & 7;
    const int wm   = w >> 2, wn = w & 3;

    // XCD-aware bijective chunk swizzle (nwg = 8*64 = 512, 512%8==0)
    const int nx  = gridDim.x;                       // 8
    const int lin = blockIdx.y * nx + blockIdx.x;
    const int cpx = (nx * gridDim.y) >> 3;           // 64
    const int swz = (lin & 7) * cpx + (lin >> 3);
    const int bx  = swz & (nx - 1), by = swz / nx;
    const int rowBase = by * 256, colBase = bx * 256;

    const int kt1 = K1 >> 6;
    const int KT  = kt1 + (K2 >> 6);

    // staging lane mapping: row = srow(+64), chunk = tid&7, global chunk XOR'd
    const int srow = tid >> 3;                        // 0..63
    const int sch  = ((tid & 7) ^ (srow & 7)) << 3;   // element offset in k
    const int ldsl = w << 9;                          // wave-uniform (1KiB/wave)

    // reader offsets (elements) — Round-1 proven mapping (rows via lane&15)
    const int arb = (wm * 16 + la) * 64;
    const int brb = (wn * 16 + la) * 64;
    const int c0  = ((0 + q) ^ la7) << 3;             // kk=0 chunk
    const int c1  = ((4 + q) ^ la7) << 3;             // kk=1 chunk

    f32x4 acc[8][4];
#pragma unroll
    for (int mi = 0; mi < 8; ++mi)
#pragma unroll
        for (int ni = 0; ni < 4; ++ni) acc[mi][ni] = (f32x4){0.f, 0.f, 0.f, 0.f};
    bf16x8 aL[4][2], aH[4][2], bL[2][2], bH[2][2];

    // prologue: tile0 {A0,B0,A1,B1} + tile1 A0 ; A0(0),B0(0) guaranteed
    STAGEH(0, 0); STAGEH(0, 1); STAGEH(0, 2); STAGEH(0, 3);
    STAGEH(1, 0);
    asm volatile("s_waitcnt vmcnt(6)" ::: "memory");
    __builtin_amdgcn_s_barrier();

    for (int t = 0; t < KT; ++t) {
        const int bf_ = t & 1;
        const ushort* A0h = &lds[bf_][0][0];
        const ushort* A1h = &lds[bf_][1][0];
        const ushort* B0h = &lds[bf_][2][0];
        const ushort* B1h = &lds[bf_][3][0];

        // ---- p0: read aL(A0,8) + bL(B0,4); stage B0(t+1); mfma aL*bL ----
#pragma unroll
        for (int f_ = 0; f_ < 4; ++f_) {
            aL[f_][0] = *(const bf16x8*)&A0h[arb + f_ * 2048 + c0];
            aL[f_][1] = *(const bf16x8*)&A0h[arb + f_ * 2048 + c1];
        }
#pragma unroll
        for (int g_ = 0; g_ < 2; ++g_) {
            bL[g_][0] = *(const bf16x8*)&B0h[brb + g_ * 4096 + c0];
            bL[g_][1] = *(const bf16x8*)&B0h[brb + g_ * 4096 + c1];
        }
        STAGEH(t + 1, 1);
        __builtin_amdgcn_s_barrier();
        __builtin_amdgcn_s_setprio(1);
#pragma unroll
        for (int kk = 0; kk < 2; ++kk)
#pragma unroll
            for (int f_ = 0; f_ < 4; ++f_)
#pragma unroll
                for (int g_ = 0; g_ < 2; ++g_)
                    acc[f_][g_] = __builtin_amdgcn_mfma_f32_16x16x32_bf16(
                        aL[f_][kk], bL[g_][kk], acc[f_][g_], 0, 0, 0);
        __builtin_amdgcn_s_setprio(0);
        asm volatile("s_waitcnt vmcnt(6)" ::: "memory");
        __builtin_amdgcn_s_barrier();

        // ---- p1: read aH(A1,8); stage A1(t+1); mfma aH*bL ----
#pragma unroll
        for (int f_ = 0; f_ < 4; ++f_) {
            aH[f_][0] = *(const bf16x8*)&A1h[arb + f_ * 2048 + c0];
            aH[f_][1] = *(const bf16x8*)&A1h[arb + f_ * 2048 + c1];
        }
        STAGEH(t + 1, 2);
        __builtin_amdgcn_s_barrier();
        __builtin_amdgcn_s_setprio(1);
#pragma unroll
        for (int kk = 0; kk < 2; ++kk)
#pragma unroll
            for (int f_ = 0; f_ < 4; ++f_)
#pragma unroll
                for (int g_ = 0; g_ < 2; ++g_)
                    acc[4 + f_][g_] = __builtin_amdgcn_mfma_f32_16x16x32_bf16(
                        aH[f_][kk], bL[g_][kk], acc[4 + f_][g_], 0, 0, 0);
        __builtin_amdgcn_s_setprio(0);
        asm volatile("s_waitcnt vmcnt(6)" ::: "memory");
        __builtin_amdgcn_s_barrier();

        // ---- p2: read bH(B1,4); stage B1(t+1); mfma aL*bH (aL held) ----
#pragma unroll
        for (int g_ = 0; g_ < 2; ++g_) {
            bH[g_][0] = *(const bf16x8*)&B1h[brb + g_ * 4096 + c0];
            bH[g_][1] = *(const bf16x8*)&B1h[brb + g_ * 4096 + c1];
        }
        STAGEH(t + 1, 3);
        __builtin_amdgcn_s_barrier();
        __builtin_amdgcn_s_setprio(1);
#pragma unroll
        for (int kk = 0; kk < 2; ++kk)
#pragma unroll
            for (int f_ = 0; f_ < 4; ++f_)
#pragma unroll
                for (int g_ = 0; g_ < 2; ++g_)
                    acc[f_][2 + g_] = __builtin_amdgcn_mfma_f32_16x16x32_bf16(
                        aL[f_][kk], bH[g_][kk], acc[f_][2 + g_], 0, 0, 0);
        __builtin_amdgcn_s_setprio(0);
        __builtin_amdgcn_s_barrier();

        // ---- p3: no reads; stage A0(t+2); mfma aH*bH ----
        STAGEH(t + 2, 0);
        __builtin_amdgcn_s_barrier();
        __builtin_amdgcn_s_setprio(1);
#pragma unroll
        for (int kk = 0; kk < 2; ++kk)
#pragma unroll
            for (int f_ = 0; f_ < 4; ++f_)
#pragma unroll
                for (int g_ = 0; g_ < 2; ++g_)
                    acc[4 + f_][2 + g_] = __builtin_amdgcn_mfma_f32_16x16x32_bf16(
                        aH[f_][kk], bH[g_][kk], acc[4 + f_][2 + g_], 0, 0, 0);
        __builtin_amdgcn_s_setprio(0);
        asm volatile("s_waitcnt vmcnt(6)" ::: "memory");
        __builtin_amdgcn_s_barrier();
    }

    __syncthreads();   // drain everything before epilogue

    // C store (per MFMA: M-row = q*4+r, N-col = la)
#pragma unroll
    for (int mi = 0; mi < 8; ++mi) {
        const int row = rowBase + (mi >> 2) * 128 + wm * 16 + (mi & 3) * 32 + q * 4;
#pragma unroll
        for (int ni = 0; ni < 4; ++ni) {
            const int col = colBase + (ni >> 1) * 128 + wn * 16 + (ni & 1) * 64 + la;
            const float bv = bias[col];
#pragma unroll
            for (int r = 0; r < 4; ++r) {
                float v = acc[mi][ni][r] + bv;
                Cbf[(size_t)(row + r) * HID + col] = f2us(v);
            }
        }
    }

    // fused BN partial stats (pre-activation, fp32 exact)
#pragma unroll
    for (int ni = 0; ni < 4; ++ni) {
        const int cib = (ni >> 1) * 128 + wn * 16 + (ni & 1) * 64 + la;
        const float bv = bias[colBase + cib];
        float t1 = 0.f, t2 = 0.f;
#pragma unroll
        for (int mi = 0; mi < 8; ++mi)
#pragma unroll
            for (int r = 0; r < 4; ++r) {
                float v = acc[mi][ni][r] + bv;
                t1 += v;
                t2 += v * v;
            }
        t1 += __shfl_xor(t1, 16);
        t1 += __shfl_xor(t1, 32);
        t2 += __shfl_xor(t2, 16);
        t2 += __shfl_xor(t2, 32);
        if (q == 0) { sb1[wm][cib] = t1; sb2[wm][cib] = t2; }
    }
    __syncthreads();
    if (tid < 256) {
        size_t o = (size_t)by * HID + colBase + tid;
        s1p[o] = sb1[0][tid] + sb1[1][tid];
        s2p[o] = sb2[0][tid] + sb2[1][tid];
    }
}

// ---------------- BatchNorm finalize ----------------

__global__ void k_bn_finalize(const float* __restrict__ p1, const float* __restrict__ p2,
                              const float* __restrict__ gamma, const float* __restrict__ beta,
                              float* __restrict__ scale, float* __restrict__ shift, int nrb) {
    int c = blockIdx.x * 256 + threadIdx.x;
    if (c >= HID) return;
    float s1 = 0.f, s2 = 0.f;
    for (int rb = 0; rb < nrb; ++rb) {
        s1 += p1[(size_t)rb * HID + c];
        s2 += p2[(size_t)rb * HID + c];
    }
    float mean = s1 * (1.f / (float)NN);
    float var = s2 * (1.f / (float)NN) - mean * mean;
    var = fmaxf(var, 0.f);
    float sc = gamma[c] * rsqrtf(var + EPS);
    scale[c] = sc;
    shift[c] = beta[c] - mean * sc;
}

// ---------------- fused BN + pooling ----------------

__global__ void k_poolbn(const ushort* __restrict__ Ybf,
                         const float* __restrict__ scale, const float* __restrict__ shift,
                         const int* __restrict__ gstart, ushort* __restrict__ hgbf) {
    int g = blockIdx.y;
    int col = blockIdx.x * 256 + threadIdx.x;
    if (g >= GG) {
        hgbf[(size_t)g * HID + col] = 0;
        return;
    }
    int s = gstart[g], e = gstart[g + 1];
    float sc = scale[col], sh = shift[col];
    float acc = 0.f;
    for (int n = s; n < e; ++n) {
        float v = sc * us2f(Ybf[(size_t)n * HID + col]) + sh;
        acc += v > 0.f ? v : SLOPE * v;
    }
    hgbf[(size_t)g * HID + col] = f2us(acc / fmaxf((float)(e - s), 1.f));
}

__global__ void k_gstart(const int* __restrict__ gid, int* __restrict__ gstart) {
    int g = threadIdx.x;
    if (g > GG) return;
    int lo = 0, hi = NN;
    while (lo < hi) {
        int mid = (lo + hi) >> 1;
        if (gid[mid] < g) lo = mid + 1; else hi = mid;
    }
    gstart[g] = lo;
}

// ---------------- split-K reduce for head GEMMs ----------------

__global__ void k_redhead(const float* __restrict__ part, int P, size_t strideZ,
                          const float* __restrict__ bias, int ldc,
                          ushort* __restrict__ obf, float* __restrict__ of, int n) {
    int i = blockIdx.x * 256 + threadIdx.x;
    if (i >= n) return;
    float s = 0.f;
    for (int p = 0; p < P; ++p) s += part[(size_t)p * strideZ + i];
    s += bias[i % ldc];
    s = s > 0.f ? s : SLOPE * s;
    if (obf) obf[i] = f2us(s);
    else     of[i] = s;
}

__global__ void k_fc3(const float* __restrict__ x2, const float* __restrict__ W,
                      const float* __restrict__ b, float* __restrict__ out) {
    int g = blockIdx.x;
    int tid = threadIdx.x;
    float part[NCLS];
#pragma unroll
    for (int c = 0; c < NCLS; ++c) part[c] = 0.f;
    for (int k = tid; k < MID; k += 256) {
        float x = x2[(size_t)g * MID + k];
        const float* wr = W + (size_t)k * NCLS;
#pragma unroll
        for (int c = 0; c < NCLS; ++c) part[c] += x * wr[c];
    }
    __shared__ float red[4][NCLS];
    int lane = tid & 63, w = tid >> 6;
#pragma unroll
    for (int c = 0; c < NCLS; ++c) {
        float v = part[c];
        for (int o = 32; o > 0; o >>= 1) v += __shfl_down(v, o, 64);
        if (lane == 0) red[w][c] = v;
    }
    __syncthreads();
    if (tid < NCLS)
        out[(size_t)g * NCLS + tid] = red[0][tid] + red[1][tid] + red[2][tid] + red[3][tid] + b[tid];
}

// ---------------- launcher ----------------

extern "C" void kernel_launch(void* const* d_in, const int* in_sizes, int n_in,
                              void* d_out, int out_size, void* d_ws, size_t ws_size,
                              hipStream_t stream) {
    const float* h        = (const float*)d_in[0];
    const int*   src      = (const int*)d_in[1];
    const int*   dst      = (const int*)d_in[2];
    const int*   graph_id = (const int*)d_in[3];
    const float* Ws1 = (const float*)d_in[4];
    const float* Wn1 = (const float*)d_in[5];
    const float* b1  = (const float*)d_in[6];
    const float* Ws2 = (const float*)d_in[7];
    const float* Wn2 = (const float*)d_in[8];
    const float* b2  = (const float*)d_in[9];
    const float* Ws3 = (const float*)d_in[10];
    const float* Wn3 = (const float*)d_in[11];
    const float* b3  = (const float*)d_in[12];
    const float* g1  = (const float*)d_in[13];
    const float* be1 = (const float*)d_in[14];
    const float* g2  = (const float*)d_in[15];
    const float* be2 = (const float*)d_in[16];
    const float* g3  = (const float*)d_in[17];
    const float* be3 = (const float*)d_in[18];
    const float* fc1_w = (const float*)d_in[19];
    const float* fc1_b = (const float*)d_in[20];
    const float* fc2_w = (const float*)d_in[21];
    const float* fc2_b = (const float*)d_in[22];
    const float* fc3_w = (const float*)d_in[23];
    const float* fc3_b = (const float*)d_in[24];
    float* out = (float*)d_out;

    size_t off_b = 0;
    auto alloc = [&](size_t bytes) -> void* {
        void* p = (char*)d_ws + off_b;
        off_b += (bytes + 255) & ~(size_t)255;
        return p;
    };
    ushort* Wt0    = (ushort*)alloc((size_t)2 * HID * HID * 2);  // 16 MiB (2 slots)
    ushort* Wt1    = Wt0 + (size_t)HID * HID;
    ushort* X      = (ushort*)alloc((size_t)NN * HID * 2);       // 64 MiB
    ushort* AggX   = (ushort*)alloc((size_t)NN * HID * 2);       // 64 MiB
    ushort* Ybf    = (ushort*)alloc((size_t)NN * HID * 2);       // 64 MiB
    float*  deg    = (float*)alloc((size_t)NN * 4);
    int*    csroff = (int*)alloc((size_t)(NN + 1) * 4);
    int*    cursor = (int*)alloc((size_t)NN * 4);
    int*    csrsrc = (int*)alloc((size_t)EE * 4);
    float*  p1     = (float*)alloc((size_t)MR * HID * 4);        // 1 MiB
    float*  p2     = (float*)alloc((size_t)MR * HID * 4);        // 1 MiB
    float*  bnsc   = (float*)alloc((size_t)HID * 4);
    float*  bnsh   = (float*)alloc((size_t)HID * 4);
    int*    gstart = (int*)alloc((size_t)(GG + 1) * 4);

    ushort* Xc128 = X;
    ushort* hgbf  = AggX;
    ushort* x1bf  = AggX + (size_t)128 * HID;
    float*  x2f   = (float*)(AggX + (size_t)2 * 128 * HID);
    float*  partF = (float*)(AggX + (size_t)3 * 128 * HID);

    // ---- CSR build ----
    k_zero_i<<<dim3(NN / 256), dim3(256), 0, stream>>>(cursor, NN);
    k_count<<<dim3(EE / 256), dim3(256), 0, stream>>>(dst, cursor);
    k_scan<<<dim3(1), dim3(1024), 0, stream>>>(cursor, csroff, deg);
    k_zero_i<<<dim3(NN / 256), dim3(256), 0, stream>>>(cursor, NN);
    k_fill<<<dim3(EE / 256), dim3(256), 0, stream>>>(src, dst, csroff, cursor, csrsrc);
    k_gstart<<<dim3(1), dim3(128), 0, stream>>>(graph_id, gstart);

    // ---- layer 1: concat input K=128, single pass (128-tile kernel) ----
    k_h2bf_c<<<dim3(NN * 64 / 256), dim3(256), 0, stream>>>(h, Xc128);
    k_agg_small_c<<<dim3(NN), dim3(64), 0, stream>>>(h, Xc128, csroff, csrsrc, deg);
    k_wt2c<<<dim3(HID / 32, 2, 2), dim3(256), 0, stream>>>(Ws1, Wn1, INF, HID, Wt0, 128);
    k_mgemm<<<dim3(HID / 128, NN / 128, 1), dim3(256), 0, stream>>>(
        Xc128, 128, Wt0, 128, 128,
        (const ushort*)nullptr, 0, (const ushort*)nullptr, 0, 0,
        b1, (float*)nullptr, Ybf, HID, 0, p1, p2, 0);
    k_bn_finalize<<<dim3(HID / 256), dim3(256), 0, stream>>>(p1, p2, g1, be1, bnsc, bnsh, MR);
    k_aggbn<<<dim3(NN), dim3(256), 0, stream>>>(Ybf, bnsc, bnsh, X, AggX, csroff, csrsrc, deg);

    // ---- layer 2: 256-tile frag-hold pipelined, two-pass K=2048+2048 ----
    k_wt2<<<dim3(HID / 32, HID / 32, 2), dim3(256), 0, stream>>>(Ws2, Wn2, HID, HID, Wt0, Wt1, HID);
    k_mgemm256<<<dim3(HID / 256, NN / 256), dim3(512), 0, stream>>>(
        X, Wt0, AggX, Wt1, HID, HID, b2, Ybf, p1, p2);
    k_bn_finalize<<<dim3(HID / 256), dim3(256), 0, stream>>>(p1, p2, g2, be2, bnsc, bnsh, NN / 256);
    k_aggbn<<<dim3(NN), dim3(256), 0, stream>>>(Ybf, bnsc, bnsh, X, AggX, csroff, csrsrc, deg);

    // ---- layer 3 ----
    k_wt2<<<dim3(HID / 32, HID / 32, 2), dim3(256), 0, stream>>>(Ws3, Wn3, HID, HID, Wt0, Wt1, HID);
    k_mgemm256<<<dim3(HID / 256, NN / 256), dim3(512), 0, stream>>>(
        X, Wt0, AggX, Wt1, HID, HID, b3, Ybf, p1, p2);
    k_bn_finalize<<<dim3(HID / 256), dim3(256), 0, stream>>>(p1, p2, g3, be3, bnsc, bnsh, NN / 256);

    // ---- fused BN + pooling ----
    k_poolbn<<<dim3(HID / 256, 128), dim3(256), 0, stream>>>(Ybf, bnsc, bnsh, gstart, hgbf);

    // ---- MLP head (split-K x4, deterministic two-stage) ----
    k_wt<<<dim3(HID / 32, HID / 32), dim3(256), 0, stream>>>(fc1_w, HID, HID, Wt0, HID);
    k_wt<<<dim3(MID / 32, HID / 32), dim3(256), 0, stream>>>(fc2_w, HID, MID, Wt1, HID);
    k_mgemm<<<dim3(HID / 128, 1, 4), dim3(256), 0, stream>>>(
        hgbf, HID, Wt0, HID, HID / 4,
        (const ushort*)nullptr, 0, (const ushort*)nullptr, 0, 0,
        (const float*)nullptr, partF, (ushort*)nullptr, HID, 0,
        (float*)nullptr, (float*)nullptr, (size_t)128 * HID);
    k_redhead<<<dim3(128 * HID / 256), dim3(256), 0, stream>>>(
        partF, 4, (size_t)128 * HID, fc1_b, HID, x1bf, (float*)nullptr, 128 * HID);
    k_mgemm<<<dim3(MID / 128, 1, 4), dim3(256), 0, stream>>>(
        x1bf, HID, Wt1, HID, HID / 4,
        (const ushort*)nullptr, 0, (const ushort*)nullptr, 0, 0,
        (const float*)nullptr, partF, (ushort*)nullptr, MID, 0,
        (float*)nullptr, (float*)nullptr, (size_t)128 * MID);
    k_redhead<<<dim3(128 * MID / 256), dim3(256), 0, stream>>>(
        partF, 4, (size_t)128 * MID, fc2_b, MID, (ushort*)nullptr, x2f, 128 * MID);
    k_fc3<<<dim3(GG), dim3(256), 0, stream>>>(x2f, fc3_w, fc3_b, out);
}